// Round 1
// baseline (1675.430 us; speedup 1.0000x reference)
//
#include <hip/hip_runtime.h>

#define N_NODES 10000
#define N_EDGES 640000
#define NODE_DIM 64
#define HIDDEN 128
#define NUM_LAYERS 4

// ---------------- edge dtype detection / normalization ----------------
// edge_index may arrive as int32 or int64 (values < 10000 so high words = 0).
// Probe odd int32 slots in [0, N_EDGES): all zero -> int64 layout.
__global__ void k_detect(const int* __restrict__ ei, int* __restrict__ flag)
{
    __shared__ int nz;
    if (threadIdx.x == 0) nz = 0;
    __syncthreads();
    int found = 0;
    for (int k = threadIdx.x; k < 2048; k += 256) {
        int pos = 2 * (k * 156) + 1;            // odd, < 640000: valid in both layouts
        if (ei[pos] != 0) found = 1;
    }
    if (found) atomicOr(&nz, 1);
    __syncthreads();
    if (threadIdx.x == 0) flag[0] = nz;          // 1 = int32 layout, 0 = int64
}

__global__ void k_normalize(const int* __restrict__ ei, const int* __restrict__ flag,
                            int* __restrict__ srcN, int* __restrict__ dstN)
{
    int e = blockIdx.x * 256 + threadIdx.x;
    if (e >= N_EDGES) return;
    if (flag[0]) {
        srcN[e] = ei[e];
        dstN[e] = ei[N_EDGES + e];
    } else {
        srcN[e] = ei[2 * e];
        dstN[e] = ei[2 * (N_EDGES + e)];
    }
}

__global__ void k_zero(int* __restrict__ p, int n)
{
    int i = blockIdx.x * 256 + threadIdx.x;
    if (i < n) p[i] = 0;
}

__global__ void k_count(const int* __restrict__ dstN, int* __restrict__ cnt)
{
    int e = blockIdx.x * 256 + threadIdx.x;
    if (e < N_EDGES) atomicAdd(&cnt[dstN[e]], 1);
}

// single-block exclusive scan over 10000 counts -> offsets (+cursor copy)
__global__ void k_scan(const int* __restrict__ cnt, int* __restrict__ offsets,
                       int* __restrict__ cursor)
{
    __shared__ int part[256];
    const int t = threadIdx.x;
    const int CH = (N_NODES + 255) / 256;        // 40
    int lo = t * CH, hi = min(N_NODES, lo + CH);
    int s = 0;
    for (int i = lo; i < hi; ++i) s += cnt[i];
    part[t] = s;
    __syncthreads();
    for (int off = 1; off < 256; off <<= 1) {
        int v = (t >= off) ? part[t - off] : 0;
        __syncthreads();
        part[t] += v;
        __syncthreads();
    }
    int base = (t == 0) ? 0 : part[t - 1];
    for (int i = lo; i < hi; ++i) {
        offsets[i] = base;
        cursor[i]  = base;
        base += cnt[i];
    }
    if (t == 255) offsets[N_NODES] = part[255];
}

__global__ void k_scatter(const int* __restrict__ srcN, const int* __restrict__ dstN,
                          int* __restrict__ cursor, int* __restrict__ csr)
{
    int e = blockIdx.x * 256 + threadIdx.x;
    if (e < N_EDGES) {
        int pos = atomicAdd(&cursor[dstN[e]], 1);
        csr[pos] = srcN[e];
    }
}

// Wa = W1[:,:128,:] - W1[:,128:,:]  (applied to x_i);  Wb = W1[:,128:,:] (x_j)
__global__ void k_prepw(const float* __restrict__ W1, float* __restrict__ Wa,
                        float* __restrict__ Wb)
{
    int i = blockIdx.x * 256 + threadIdx.x;      // over L*128*128
    if (i >= NUM_LAYERS * 128 * 128) return;
    int l = i >> 14, rem = i & 16383;            // rem = k*128 + c
    float top = W1[l * 32768 + rem];
    float bot = W1[l * 32768 + 16384 + rem];
    Wa[i] = top - bot;
    Wb[i] = bot;
}

// ---------------- node GEMM: C[M][128] = X[M][K] @ W[K][128] (+bias) ----------------
template <int K>
__global__ __launch_bounds__(256) void k_gemm_nodes(
    const float* __restrict__ X, const float* __restrict__ W,
    const float* __restrict__ bias, float* __restrict__ C, int M)
{
    constexpr int LDX = K + 4;
    __shared__ float Xs[64 * LDX];
    const int t = threadIdx.x;
    const int row0 = blockIdx.x * 64;
    constexpr int F4R = K / 4;
    for (int idx = t; idx < 64 * F4R; idx += 256) {
        int r = idx / F4R, f = idx % F4R;
        int gr = row0 + r;
        float4 v = make_float4(0.f, 0.f, 0.f, 0.f);
        if (gr < M) v = *(const float4*)(X + (size_t)gr * K + 4 * f);
        *(float4*)(Xs + r * LDX + 4 * f) = v;
    }
    __syncthreads();
    const int rg = t >> 4, cg = t & 15;
    float acc[4][8];
#pragma unroll
    for (int i = 0; i < 4; ++i)
#pragma unroll
        for (int j = 0; j < 8; ++j) acc[i][j] = 0.f;

#pragma unroll 8
    for (int k = 0; k < K; ++k) {
        float4 w0 = *(const float4*)(W + k * 128 + cg * 8);
        float4 w1 = *(const float4*)(W + k * 128 + cg * 8 + 4);
        float xs[4];
#pragma unroll
        for (int i = 0; i < 4; ++i) xs[i] = Xs[(rg * 4 + i) * LDX + k];
#pragma unroll
        for (int i = 0; i < 4; ++i) {
            acc[i][0] += xs[i] * w0.x; acc[i][1] += xs[i] * w0.y;
            acc[i][2] += xs[i] * w0.z; acc[i][3] += xs[i] * w0.w;
            acc[i][4] += xs[i] * w1.x; acc[i][5] += xs[i] * w1.y;
            acc[i][6] += xs[i] * w1.z; acc[i][7] += xs[i] * w1.w;
        }
    }
    float b[8];
#pragma unroll
    for (int j = 0; j < 8; ++j) b[j] = 0.f;
    if (bias) {
        float4 b0 = *(const float4*)(bias + cg * 8);
        float4 b1 = *(const float4*)(bias + cg * 8 + 4);
        b[0] = b0.x; b[1] = b0.y; b[2] = b0.z; b[3] = b0.w;
        b[4] = b1.x; b[5] = b1.y; b[6] = b1.z; b[7] = b1.w;
    }
#pragma unroll
    for (int i = 0; i < 4; ++i) {
        int r = row0 + rg * 4 + i;
        if (r < M) {
            float4 o0 = make_float4(acc[i][0] + b[0], acc[i][1] + b[1],
                                    acc[i][2] + b[2], acc[i][3] + b[3]);
            float4 o1 = make_float4(acc[i][4] + b[4], acc[i][5] + b[5],
                                    acc[i][6] + b[6], acc[i][7] + b[7]);
            *(float4*)(C + (size_t)r * 128 + cg * 8) = o0;
            *(float4*)(C + (size_t)r * 128 + cg * 8 + 4) = o1;
        }
    }
}

// ---------------- EdgeConv gather kernel (the hot one) ----------------
// Per node n: over incoming edges (+self loop), t = relu(A[n]+B[src]);
// m = t @ W2; h_out[n] = colwise max over edges + b2.
#define EB 64
#define LDT 132

__global__ __launch_bounds__(256) void k_edge(
    const float* __restrict__ A, const float* __restrict__ Bm,
    const int* __restrict__ csr_src, const int* __restrict__ offsets,
    const float* __restrict__ W2g, const float* __restrict__ b2,
    float* __restrict__ hout)
{
    __shared__ float Ts[EB * LDT];       // 33792 B
    __shared__ float W2s[32 * 128];      // 16384 B
    const int n = blockIdx.x;
    const int t = threadIdx.x;
    const int beg = offsets[n];
    const int deg = offsets[n + 1] - beg;
    const int total = deg + 1;           // + self loop (src = n), appended last
    const int rg = t >> 4;               // edge group: edges rg*4 .. rg*4+3
    const int cg = t & 15;               // cols cg*4..+3 and 64+cg*4..+3

    float cmax[8];
#pragma unroll
    for (int j = 0; j < 8; ++j) cmax[j] = -3.4e38f;

    const float* An = A + (size_t)n * HIDDEN;

    for (int c0 = 0; c0 < total; c0 += EB) {
        const int chunk = min(EB, total - c0);
        // ---- stage T (4 threads per edge, float4 granularity) ----
        {
            const int ec = t >> 2;
            const int q  = t & 3;
            if (ec < chunk) {
                const int gi = c0 + ec;
                const int src = (gi < deg) ? csr_src[beg + gi] : n;
                const float* Bs = Bm + (size_t)src * HIDDEN;
#pragma unroll
                for (int j2 = 0; j2 < 8; ++j2) {
                    const int f = q + 4 * j2;
                    float4 a = *(const float4*)(An + 4 * f);
                    float4 b = *(const float4*)(Bs + 4 * f);
                    float4 r;
                    r.x = fmaxf(a.x + b.x, 0.f);
                    r.y = fmaxf(a.y + b.y, 0.f);
                    r.z = fmaxf(a.z + b.z, 0.f);
                    r.w = fmaxf(a.w + b.w, 0.f);
                    *(float4*)(Ts + ec * LDT + 4 * f) = r;
                }
            } else {
                float4 z = make_float4(0.f, 0.f, 0.f, 0.f);
#pragma unroll
                for (int j2 = 0; j2 < 8; ++j2) {
                    const int f = q + 4 * j2;
                    *(float4*)(Ts + ec * LDT + 4 * f) = z;
                }
            }
        }

        float acc[4][8];
#pragma unroll
        for (int i = 0; i < 4; ++i)
#pragma unroll
            for (int j = 0; j < 8; ++j) acc[i][j] = 0.f;

        const bool active = (rg * 4 < chunk);

        for (int kt = 0; kt < 4; ++kt) {
            __syncthreads();   // prior W2s reads done; Ts writes visible
            // ---- stage W2 tile [kt*32 .. kt*32+32) x 128 ----
            for (int idx = t; idx < 1024; idx += 256) {
                int r = idx >> 5, f = idx & 31;
                *(float4*)(W2s + r * 128 + 4 * f) =
                    *(const float4*)(W2g + (size_t)(kt * 32 + r) * 128 + 4 * f);
            }
            __syncthreads();   // W2s ready
            if (active) {
#pragma unroll 8
                for (int kk = 0; kk < 32; ++kk) {
                    const int k = kt * 32 + kk;
                    float4 w0 = *(const float4*)(W2s + kk * 128 + cg * 4);
                    float4 w1 = *(const float4*)(W2s + kk * 128 + 64 + cg * 4);
                    float xs0 = Ts[(rg * 4 + 0) * LDT + k];
                    float xs1 = Ts[(rg * 4 + 1) * LDT + k];
                    float xs2 = Ts[(rg * 4 + 2) * LDT + k];
                    float xs3 = Ts[(rg * 4 + 3) * LDT + k];
                    acc[0][0] += xs0 * w0.x; acc[0][1] += xs0 * w0.y;
                    acc[0][2] += xs0 * w0.z; acc[0][3] += xs0 * w0.w;
                    acc[0][4] += xs0 * w1.x; acc[0][5] += xs0 * w1.y;
                    acc[0][6] += xs0 * w1.z; acc[0][7] += xs0 * w1.w;
                    acc[1][0] += xs1 * w0.x; acc[1][1] += xs1 * w0.y;
                    acc[1][2] += xs1 * w0.z; acc[1][3] += xs1 * w0.w;
                    acc[1][4] += xs1 * w1.x; acc[1][5] += xs1 * w1.y;
                    acc[1][6] += xs1 * w1.z; acc[1][7] += xs1 * w1.w;
                    acc[2][0] += xs2 * w0.x; acc[2][1] += xs2 * w0.y;
                    acc[2][2] += xs2 * w0.z; acc[2][3] += xs2 * w0.w;
                    acc[2][4] += xs2 * w1.x; acc[2][5] += xs2 * w1.y;
                    acc[2][6] += xs2 * w1.z; acc[2][7] += xs2 * w1.w;
                    acc[3][0] += xs3 * w0.x; acc[3][1] += xs3 * w0.y;
                    acc[3][2] += xs3 * w0.z; acc[3][3] += xs3 * w0.w;
                    acc[3][4] += xs3 * w1.x; acc[3][5] += xs3 * w1.y;
                    acc[3][6] += xs3 * w1.z; acc[3][7] += xs3 * w1.w;
                }
            }
        }
        if (active) {
#pragma unroll
            for (int i = 0; i < 4; ++i) {
                if (c0 + rg * 4 + i < total) {
#pragma unroll
                    for (int j = 0; j < 8; ++j) cmax[j] = fmaxf(cmax[j], acc[i][j]);
                }
            }
        }
        __syncthreads();       // all Ts/W2s reads done before next chunk / reduce
    }

    // ---- cross-thread max over the 16 edge groups ----
    float* red = Ts;           // [16][128]
#pragma unroll
    for (int j = 0; j < 4; ++j) {
        red[rg * 128 + cg * 4 + j]      = cmax[j];
        red[rg * 128 + 64 + cg * 4 + j] = cmax[4 + j];
    }
    __syncthreads();
    if (t < 128) {
        float m = red[t];
#pragma unroll
        for (int r = 1; r < 16; ++r) m = fmaxf(m, red[r * 128 + t]);
        hout[(size_t)n * HIDDEN + t] = m + b2[t];
    }
}

// ---------------- launch ----------------
extern "C" void kernel_launch(void* const* d_in, const int* in_sizes, int n_in,
                              void* d_out, int out_size, void* d_ws, size_t ws_size,
                              hipStream_t stream)
{
    const float* x     = (const float*)d_in[0];
    const int*   ei    = (const int*)d_in[1];
    const float* W_emb = (const float*)d_in[2];
    const float* b_emb = (const float*)d_in[3];
    const float* W1    = (const float*)d_in[4];
    const float* b1    = (const float*)d_in[5];
    const float* W2    = (const float*)d_in[6];
    const float* b2    = (const float*)d_in[7];
    const float* W_fc  = (const float*)d_in[8];
    const float* b_fc  = (const float*)d_in[9];
    float* out = (float*)d_out;

    char* p = (char*)d_ws;
    auto alloc = [&](size_t bytes) {
        char* r = p;
        p += (bytes + 255) & ~(size_t)255;
        return r;
    };
    float* h    = (float*)alloc((size_t)N_NODES * HIDDEN * 4);
    float* Ab   = (float*)alloc((size_t)N_NODES * HIDDEN * 4);
    float* Bb   = (float*)alloc((size_t)N_NODES * HIDDEN * 4);
    float* Wa   = (float*)alloc((size_t)NUM_LAYERS * 16384 * 4);
    float* Wb   = (float*)alloc((size_t)NUM_LAYERS * 16384 * 4);
    int* offs   = (int*)alloc((N_NODES + 1) * 4);
    int* cursor = (int*)alloc(N_NODES * 4);
    int* cnt    = (int*)alloc(N_NODES * 4);
    int* csr    = (int*)alloc((size_t)N_EDGES * 4);
    int* srcN   = (int*)alloc((size_t)N_EDGES * 4);
    int* dstN   = (int*)alloc((size_t)N_EDGES * 4);
    int* flag   = (int*)alloc(4);

    const int EBLK = (N_EDGES + 255) / 256;

    k_detect<<<1, 256, 0, stream>>>(ei, flag);
    k_normalize<<<EBLK, 256, 0, stream>>>(ei, flag, srcN, dstN);
    k_zero<<<(N_NODES + 255) / 256, 256, 0, stream>>>(cnt, N_NODES);
    k_count<<<EBLK, 256, 0, stream>>>(dstN, cnt);
    k_scan<<<1, 256, 0, stream>>>(cnt, offs, cursor);
    k_scatter<<<EBLK, 256, 0, stream>>>(srcN, dstN, cursor, csr);
    k_prepw<<<(NUM_LAYERS * 16384 + 255) / 256, 256, 0, stream>>>(W1, Wa, Wb);

    const int GB = (N_NODES + 63) / 64;   // 157
    k_gemm_nodes<NODE_DIM><<<GB, 256, 0, stream>>>(x, W_emb, b_emb, h, N_NODES);

    for (int l = 0; l < NUM_LAYERS; ++l) {
        k_gemm_nodes<HIDDEN><<<GB, 256, 0, stream>>>(h, Wa + l * 16384, b1 + l * 128, Ab, N_NODES);
        k_gemm_nodes<HIDDEN><<<GB, 256, 0, stream>>>(h, Wb + l * 16384, nullptr, Bb, N_NODES);
        k_edge<<<N_NODES, 256, 0, stream>>>(Ab, Bb, csr, offs, W2 + (size_t)l * 16384,
                                            b2 + l * 128, h);
    }
    k_gemm_nodes<HIDDEN><<<GB, 256, 0, stream>>>(h, W_fc, b_fc, out, N_NODES);
}

// Round 2
// 1400.543 us; speedup vs baseline: 1.1963x; 1.1963x over previous
//
#include <hip/hip_runtime.h>

#define N_NODES 10000
#define N_EDGES 640000
#define NODE_DIM 64
#define HIDDEN 128
#define NUM_LAYERS 4
#define NT (N_EDGES + N_NODES)   // 650000 edge slots incl. self loops

// ---------------- edge dtype detection / normalization ----------------
// edge_index may arrive as int32 or int64 (values < 10000 so high words = 0).
// Probe odd int32 slots in [0, N_EDGES): all zero -> int64 layout.
__global__ void k_detect(const int* __restrict__ ei, int* __restrict__ flag)
{
    __shared__ int nz;
    if (threadIdx.x == 0) nz = 0;
    __syncthreads();
    int found = 0;
    for (int k = threadIdx.x; k < 2048; k += 256) {
        int pos = 2 * (k * 156) + 1;            // odd, < 640000: valid in both layouts
        if (ei[pos] != 0) found = 1;
    }
    if (found) atomicOr(&nz, 1);
    __syncthreads();
    if (threadIdx.x == 0) flag[0] = nz;          // 1 = int32 layout, 0 = int64
}

__global__ void k_normalize(const int* __restrict__ ei, const int* __restrict__ flag,
                            int* __restrict__ srcN, int* __restrict__ dstN)
{
    int e = blockIdx.x * 256 + threadIdx.x;
    if (e >= N_EDGES) return;
    if (flag[0]) {
        srcN[e] = ei[e];
        dstN[e] = ei[N_EDGES + e];
    } else {
        srcN[e] = ei[2 * e];
        dstN[e] = ei[2 * (N_EDGES + e)];
    }
}

__global__ void k_zero(int* __restrict__ p, int n)
{
    int i = blockIdx.x * 256 + threadIdx.x;
    if (i < n) p[i] = 0;
}

__global__ void k_count(const int* __restrict__ dstN, int* __restrict__ cnt)
{
    int e = blockIdx.x * 256 + threadIdx.x;
    if (e < N_EDGES) atomicAdd(&cnt[dstN[e]], 1);
}

// single-block exclusive scan over (cnt[i]+1) -> cursor (self loop included)
__global__ void k_scan(const int* __restrict__ cnt, int* __restrict__ cursor)
{
    __shared__ int part[256];
    const int t = threadIdx.x;
    const int CH = (N_NODES + 255) / 256;        // 40
    int lo = t * CH, hi = min(N_NODES, lo + CH);
    int s = 0;
    for (int i = lo; i < hi; ++i) s += cnt[i] + 1;
    part[t] = s;
    __syncthreads();
    for (int off = 1; off < 256; off <<= 1) {
        int v = (t >= off) ? part[t - off] : 0;
        __syncthreads();
        part[t] += v;
        __syncthreads();
    }
    int base = (t == 0) ? 0 : part[t - 1];
    for (int i = lo; i < hi; ++i) {
        cursor[i] = base;
        base += cnt[i] + 1;
    }
}

__global__ void k_scatter(const int* __restrict__ srcN, const int* __restrict__ dstN,
                          int* __restrict__ cursor,
                          int* __restrict__ esrc, int* __restrict__ edst)
{
    int e = blockIdx.x * 256 + threadIdx.x;
    if (e < N_EDGES) {
        int d = dstN[e];
        int pos = atomicAdd(&cursor[d], 1);
        esrc[pos] = srcN[e];
        edst[pos] = d;
    }
}

__global__ void k_selfloop(int* __restrict__ cursor,
                           int* __restrict__ esrc, int* __restrict__ edst)
{
    int n = blockIdx.x * 256 + threadIdx.x;
    if (n < N_NODES) {
        int pos = atomicAdd(&cursor[n], 1);
        esrc[pos] = n;
        edst[pos] = n;
    }
}

// Wa = W1[:,:128,:] - W1[:,128:,:]  (applied to x_i);  Wb = W1[:,128:,:] (x_j)
__global__ void k_prepw(const float* __restrict__ W1, float* __restrict__ Wa,
                        float* __restrict__ Wb)
{
    int i = blockIdx.x * 256 + threadIdx.x;      // over L*128*128
    if (i >= NUM_LAYERS * 128 * 128) return;
    int l = i >> 14, rem = i & 16383;            // rem = k*128 + c
    float top = W1[l * 32768 + rem];
    float bot = W1[l * 32768 + 16384 + rem];
    Wa[i] = top - bot;
    Wb[i] = bot;
}

// decode sign-magnitude-encoded max + bias -> h
__global__ void k_decode(const unsigned int* __restrict__ enc,
                         const float* __restrict__ b2, float* __restrict__ h)
{
    int i = blockIdx.x * 256 + threadIdx.x;
    if (i >= N_NODES * HIDDEN) return;
    unsigned int u = enc[i];
    unsigned int bits = (u & 0x80000000u) ? (u ^ 0x80000000u) : ~u;
    h[i] = __uint_as_float(bits) + b2[i & (HIDDEN - 1)];
}

__device__ __forceinline__ unsigned int encf(float f)
{
    unsigned int b = __float_as_uint(f);
    return b ^ ((unsigned int)((int)b >> 31) | 0x80000000u);
}

// ---------------- node GEMM: C[M][128] = X[M][K] @ W[K][128] (+bias) ----------------
template <int K>
__global__ __launch_bounds__(256) void k_gemm_nodes(
    const float* __restrict__ X, const float* __restrict__ W,
    const float* __restrict__ bias, float* __restrict__ C, int M)
{
    constexpr int LDX = K + 4;
    __shared__ float Xs[64 * LDX];
    const int t = threadIdx.x;
    const int row0 = blockIdx.x * 64;
    constexpr int F4R = K / 4;
    for (int idx = t; idx < 64 * F4R; idx += 256) {
        int r = idx / F4R, f = idx % F4R;
        int gr = row0 + r;
        float4 v = make_float4(0.f, 0.f, 0.f, 0.f);
        if (gr < M) v = *(const float4*)(X + (size_t)gr * K + 4 * f);
        *(float4*)(Xs + r * LDX + 4 * f) = v;
    }
    __syncthreads();
    const int rg = t >> 4, cg = t & 15;
    float acc[4][8];
#pragma unroll
    for (int i = 0; i < 4; ++i)
#pragma unroll
        for (int j = 0; j < 8; ++j) acc[i][j] = 0.f;

#pragma unroll 8
    for (int k = 0; k < K; ++k) {
        float4 w0 = *(const float4*)(W + k * 128 + cg * 8);
        float4 w1 = *(const float4*)(W + k * 128 + cg * 8 + 4);
        float xs[4];
#pragma unroll
        for (int i = 0; i < 4; ++i) xs[i] = Xs[(rg * 4 + i) * LDX + k];
#pragma unroll
        for (int i = 0; i < 4; ++i) {
            acc[i][0] += xs[i] * w0.x; acc[i][1] += xs[i] * w0.y;
            acc[i][2] += xs[i] * w0.z; acc[i][3] += xs[i] * w0.w;
            acc[i][4] += xs[i] * w1.x; acc[i][5] += xs[i] * w1.y;
            acc[i][6] += xs[i] * w1.z; acc[i][7] += xs[i] * w1.w;
        }
    }
    float b[8];
#pragma unroll
    for (int j = 0; j < 8; ++j) b[j] = 0.f;
    if (bias) {
        float4 b0 = *(const float4*)(bias + cg * 8);
        float4 b1 = *(const float4*)(bias + cg * 8 + 4);
        b[0] = b0.x; b[1] = b0.y; b[2] = b0.z; b[3] = b0.w;
        b[4] = b1.x; b[5] = b1.y; b[6] = b1.z; b[7] = b1.w;
    }
#pragma unroll
    for (int i = 0; i < 4; ++i) {
        int r = row0 + rg * 4 + i;
        if (r < M) {
            float4 o0 = make_float4(acc[i][0] + b[0], acc[i][1] + b[1],
                                    acc[i][2] + b[2], acc[i][3] + b[3]);
            float4 o1 = make_float4(acc[i][4] + b[4], acc[i][5] + b[5],
                                    acc[i][6] + b[6], acc[i][7] + b[7]);
            *(float4*)(C + (size_t)r * 128 + cg * 8) = o0;
            *(float4*)(C + (size_t)r * 128 + cg * 8 + 4) = o1;
        }
    }
}

// ---------------- EdgeConv, edge-parallel (the hot one) ----------------
// Block b handles edge slots [b*64, b*64+64) of the dst-sorted slot list.
// t = relu(A[dst]+B[src]); m = t @ W2; segmented col-max by dst -> atomicMax.
#define EB 64
#define LDT 132

__global__ __launch_bounds__(256) void k_edge2(
    const float* __restrict__ A, const float* __restrict__ Bm,
    const int* __restrict__ esrc, const int* __restrict__ edst,
    const float* __restrict__ W2g, unsigned int* __restrict__ enc)
{
    __shared__ float Ts[EB * LDT];       // 33792 B
    __shared__ float W2s[32 * 128];      // 16384 B
    __shared__ int dsts[EB];
    const int t = threadIdx.x;
    const int s0 = blockIdx.x * EB;

    // ---- stage T (4 threads per edge slot, float4 granularity) ----
    {
        const int ec = t >> 2;
        const int q  = t & 3;
        const int slot = s0 + ec;
        int dst = -1, src = 0;
        if (slot < NT) { dst = edst[slot]; src = esrc[slot]; }
        if (q == 0) dsts[ec] = dst;
        if (dst >= 0) {
            const float* Ar = A + (size_t)dst * HIDDEN;
            const float* Br = Bm + (size_t)src * HIDDEN;
#pragma unroll
            for (int j2 = 0; j2 < 8; ++j2) {
                const int f = q + 4 * j2;
                float4 a = *(const float4*)(Ar + 4 * f);
                float4 b = *(const float4*)(Br + 4 * f);
                float4 r;
                r.x = fmaxf(a.x + b.x, 0.f);
                r.y = fmaxf(a.y + b.y, 0.f);
                r.z = fmaxf(a.z + b.z, 0.f);
                r.w = fmaxf(a.w + b.w, 0.f);
                *(float4*)(Ts + ec * LDT + 4 * f) = r;
            }
        } else {
            float4 z = make_float4(0.f, 0.f, 0.f, 0.f);
#pragma unroll
            for (int j2 = 0; j2 < 8; ++j2) {
                const int f = q + 4 * j2;
                *(float4*)(Ts + ec * LDT + 4 * f) = z;
            }
        }
    }

    const int rg = t >> 4;               // edge group: edges rg*4 .. rg*4+3
    const int cg = t & 15;               // cols cg*4..+3 and 64+cg*4..+3

    float acc[4][8];
#pragma unroll
    for (int i = 0; i < 4; ++i)
#pragma unroll
        for (int j = 0; j < 8; ++j) acc[i][j] = 0.f;

    for (int kt = 0; kt < 4; ++kt) {
        __syncthreads();   // kt=0: Ts staged; kt>0: prior W2s reads done
        for (int idx = t; idx < 1024; idx += 256) {
            int r = idx >> 5, f = idx & 31;
            *(float4*)(W2s + r * 128 + 4 * f) =
                *(const float4*)(W2g + (size_t)(kt * 32 + r) * 128 + 4 * f);
        }
        __syncthreads();   // W2s ready
#pragma unroll 8
        for (int kk = 0; kk < 32; ++kk) {
            const int k = kt * 32 + kk;
            float4 w0 = *(const float4*)(W2s + kk * 128 + cg * 4);
            float4 w1 = *(const float4*)(W2s + kk * 128 + 64 + cg * 4);
            float xs0 = Ts[(rg * 4 + 0) * LDT + k];
            float xs1 = Ts[(rg * 4 + 1) * LDT + k];
            float xs2 = Ts[(rg * 4 + 2) * LDT + k];
            float xs3 = Ts[(rg * 4 + 3) * LDT + k];
            acc[0][0] += xs0 * w0.x; acc[0][1] += xs0 * w0.y;
            acc[0][2] += xs0 * w0.z; acc[0][3] += xs0 * w0.w;
            acc[0][4] += xs0 * w1.x; acc[0][5] += xs0 * w1.y;
            acc[0][6] += xs0 * w1.z; acc[0][7] += xs0 * w1.w;
            acc[1][0] += xs1 * w0.x; acc[1][1] += xs1 * w0.y;
            acc[1][2] += xs1 * w0.z; acc[1][3] += xs1 * w0.w;
            acc[1][4] += xs1 * w1.x; acc[1][5] += xs1 * w1.y;
            acc[1][6] += xs1 * w1.z; acc[1][7] += xs1 * w1.w;
            acc[2][0] += xs2 * w0.x; acc[2][1] += xs2 * w0.y;
            acc[2][2] += xs2 * w0.z; acc[2][3] += xs2 * w0.w;
            acc[2][4] += xs2 * w1.x; acc[2][5] += xs2 * w1.y;
            acc[2][6] += xs2 * w1.z; acc[2][7] += xs2 * w1.w;
            acc[3][0] += xs3 * w0.x; acc[3][1] += xs3 * w0.y;
            acc[3][2] += xs3 * w0.z; acc[3][3] += xs3 * w0.w;
            acc[3][4] += xs3 * w1.x; acc[3][5] += xs3 * w1.y;
            acc[3][6] += xs3 * w1.z; acc[3][7] += xs3 * w1.w;
        }
    }

    __syncthreads();       // all Ts reads of the k-loop complete
    // ---- spill m back into Ts ----
#pragma unroll
    for (int i = 0; i < 4; ++i) {
        float4 o0 = make_float4(acc[i][0], acc[i][1], acc[i][2], acc[i][3]);
        float4 o1 = make_float4(acc[i][4], acc[i][5], acc[i][6], acc[i][7]);
        *(float4*)(Ts + (rg * 4 + i) * LDT + cg * 4) = o0;
        *(float4*)(Ts + (rg * 4 + i) * LDT + 64 + cg * 4) = o1;
    }
    __syncthreads();

    // ---- segmented column-walk max -> atomicMax (dst-sorted slots) ----
    const int col  = t & 127;
    const int e0   = (t >> 7) * 32;      // half 0: edges 0-31, half 1: 32-63
    float run = -3.4e38f;
    int curd = dsts[e0];
    for (int e = e0; e < e0 + 32; ++e) {
        int d = dsts[e];
        if (d != curd) {
            if (curd >= 0)
                atomicMax(&enc[(size_t)curd * HIDDEN + col], encf(run));
            curd = d;
            run = -3.4e38f;
        }
        run = fmaxf(run, Ts[e * LDT + col]);
    }
    if (curd >= 0)
        atomicMax(&enc[(size_t)curd * HIDDEN + col], encf(run));
}

// ---------------- launch ----------------
extern "C" void kernel_launch(void* const* d_in, const int* in_sizes, int n_in,
                              void* d_out, int out_size, void* d_ws, size_t ws_size,
                              hipStream_t stream)
{
    const float* x     = (const float*)d_in[0];
    const int*   ei    = (const int*)d_in[1];
    const float* W_emb = (const float*)d_in[2];
    const float* b_emb = (const float*)d_in[3];
    const float* W1    = (const float*)d_in[4];
    const float* b1    = (const float*)d_in[5];
    const float* W2    = (const float*)d_in[6];
    const float* b2    = (const float*)d_in[7];
    const float* W_fc  = (const float*)d_in[8];
    const float* b_fc  = (const float*)d_in[9];
    float* out = (float*)d_out;

    char* p = (char*)d_ws;
    auto alloc = [&](size_t bytes) {
        char* r = p;
        p += (bytes + 255) & ~(size_t)255;
        return r;
    };
    float* h    = (float*)alloc((size_t)N_NODES * HIDDEN * 4);
    float* Ab   = (float*)alloc((size_t)N_NODES * HIDDEN * 4);
    float* Bb   = (float*)alloc((size_t)N_NODES * HIDDEN * 4);
    unsigned int* enc = (unsigned int*)alloc((size_t)N_NODES * HIDDEN * 4);
    float* Wa   = (float*)alloc((size_t)NUM_LAYERS * 16384 * 4);
    float* Wb   = (float*)alloc((size_t)NUM_LAYERS * 16384 * 4);
    int* cursor = (int*)alloc(N_NODES * 4);
    int* cnt    = (int*)alloc(N_NODES * 4);
    int* esrc   = (int*)alloc((size_t)NT * 4);
    int* edst   = (int*)alloc((size_t)NT * 4);
    int* srcN   = (int*)alloc((size_t)N_EDGES * 4);
    int* dstN   = (int*)alloc((size_t)N_EDGES * 4);
    int* flag   = (int*)alloc(4);

    const int EBLK = (N_EDGES + 255) / 256;

    k_detect<<<1, 256, 0, stream>>>(ei, flag);
    k_normalize<<<EBLK, 256, 0, stream>>>(ei, flag, srcN, dstN);
    k_zero<<<(N_NODES + 255) / 256, 256, 0, stream>>>(cnt, N_NODES);
    k_count<<<EBLK, 256, 0, stream>>>(dstN, cnt);
    k_scan<<<1, 256, 0, stream>>>(cnt, cursor);
    k_scatter<<<EBLK, 256, 0, stream>>>(srcN, dstN, cursor, esrc, edst);
    k_selfloop<<<(N_NODES + 255) / 256, 256, 0, stream>>>(cursor, esrc, edst);
    k_prepw<<<(NUM_LAYERS * 16384 + 255) / 256, 256, 0, stream>>>(W1, Wa, Wb);

    const int GB  = (N_NODES + 63) / 64;          // 157
    const int EG  = (NT + EB - 1) / EB;           // 10157
    const int NZ  = (N_NODES * HIDDEN + 255) / 256;

    k_gemm_nodes<NODE_DIM><<<GB, 256, 0, stream>>>(x, W_emb, b_emb, h, N_NODES);

    for (int l = 0; l < NUM_LAYERS; ++l) {
        k_gemm_nodes<HIDDEN><<<GB, 256, 0, stream>>>(h, Wa + l * 16384, b1 + l * 128, Ab, N_NODES);
        k_gemm_nodes<HIDDEN><<<GB, 256, 0, stream>>>(h, Wb + l * 16384, nullptr, Bb, N_NODES);
        k_zero<<<NZ, 256, 0, stream>>>((int*)enc, N_NODES * HIDDEN);
        k_edge2<<<EG, 256, 0, stream>>>(Ab, Bb, esrc, edst, W2 + (size_t)l * 16384, enc);
        k_decode<<<NZ, 256, 0, stream>>>(enc, b2 + l * 128, h);
    }
    k_gemm_nodes<HIDDEN><<<GB, 256, 0, stream>>>(h, W_fc, b_fc, out, N_NODES);
}

// Round 3
// 992.985 us; speedup vs baseline: 1.6873x; 1.4104x over previous
//
#include <hip/hip_runtime.h>

#define N_NODES 10000
#define N_EDGES 640000
#define NODE_DIM 64
#define HIDDEN 128
#define NUM_LAYERS 4
#define NT (N_EDGES + N_NODES)   // 650000 edge slots incl. self loops
#define EB3 64                   // edge slots per block in k_edge3

typedef __attribute__((ext_vector_type(8))) short short8v;
typedef __attribute__((ext_vector_type(16))) float f32x16;

// ---------------- edge dtype detection / normalization ----------------
__global__ void k_detect(const int* __restrict__ ei, int* __restrict__ flag)
{
    __shared__ int nz;
    if (threadIdx.x == 0) nz = 0;
    __syncthreads();
    int found = 0;
    for (int k = threadIdx.x; k < 2048; k += 256) {
        int pos = 2 * (k * 156) + 1;
        if (ei[pos] != 0) found = 1;
    }
    if (found) atomicOr(&nz, 1);
    __syncthreads();
    if (threadIdx.x == 0) flag[0] = nz;          // 1 = int32 layout, 0 = int64
}

__global__ void k_normalize(const int* __restrict__ ei, const int* __restrict__ flag,
                            int* __restrict__ srcN, int* __restrict__ dstN)
{
    int e = blockIdx.x * 256 + threadIdx.x;
    if (e >= N_EDGES) return;
    if (flag[0]) {
        srcN[e] = ei[e];
        dstN[e] = ei[N_EDGES + e];
    } else {
        srcN[e] = ei[2 * e];
        dstN[e] = ei[2 * (N_EDGES + e)];
    }
}

__global__ void k_zero(int* __restrict__ p, int n)
{
    int i = blockIdx.x * 256 + threadIdx.x;
    if (i < n) p[i] = 0;
}

__global__ void k_count(const int* __restrict__ dstN, int* __restrict__ cnt)
{
    int e = blockIdx.x * 256 + threadIdx.x;
    if (e < N_EDGES) atomicAdd(&cnt[dstN[e]], 1);
}

__global__ void k_scan(const int* __restrict__ cnt, int* __restrict__ cursor)
{
    __shared__ int part[256];
    const int t = threadIdx.x;
    const int CH = (N_NODES + 255) / 256;        // 40
    int lo = t * CH, hi = min(N_NODES, lo + CH);
    int s = 0;
    for (int i = lo; i < hi; ++i) s += cnt[i] + 1;
    part[t] = s;
    __syncthreads();
    for (int off = 1; off < 256; off <<= 1) {
        int v = (t >= off) ? part[t - off] : 0;
        __syncthreads();
        part[t] += v;
        __syncthreads();
    }
    int base = (t == 0) ? 0 : part[t - 1];
    for (int i = lo; i < hi; ++i) {
        cursor[i] = base;
        base += cnt[i] + 1;
    }
}

__global__ void k_scatter(const int* __restrict__ srcN, const int* __restrict__ dstN,
                          int* __restrict__ cursor,
                          int* __restrict__ esrc, int* __restrict__ edst)
{
    int e = blockIdx.x * 256 + threadIdx.x;
    if (e < N_EDGES) {
        int d = dstN[e];
        int pos = atomicAdd(&cursor[d], 1);
        esrc[pos] = srcN[e];
        edst[pos] = d;
    }
}

__global__ void k_selfloop(int* __restrict__ cursor,
                           int* __restrict__ esrc, int* __restrict__ edst)
{
    int n = blockIdx.x * 256 + threadIdx.x;
    if (n < N_NODES) {
        int pos = atomicAdd(&cursor[n], 1);
        esrc[pos] = n;
        edst[pos] = n;
    }
}

// Wa = W1[:,:128,:] - W1[:,128:,:] (x_i side);  Wb = W1[:,128:,:] (x_j side)
__global__ void k_prepw(const float* __restrict__ W1, float* __restrict__ Wa,
                        float* __restrict__ Wb)
{
    int i = blockIdx.x * 256 + threadIdx.x;      // over L*128*128
    if (i >= NUM_LAYERS * 128 * 128) return;
    int l = i >> 14, rem = i & 16383;
    float top = W1[l * 32768 + rem];
    float bot = W1[l * 32768 + 16384 + rem];
    Wa[i] = top - bot;
    Wb[i] = bot;
}

__device__ __forceinline__ unsigned short bf16rne(float f)
{
    unsigned int u = __float_as_uint(f);
    unsigned int r = u + 0x7FFFu + ((u >> 16) & 1u);
    return (unsigned short)(r >> 16);
}

// W2 -> chunk-major transposed hi/lo bf16: W2cm[l][c=k/16][h][n][k%16]
__global__ void k_prepw2(const float* __restrict__ W2, short* __restrict__ W2cm)
{
    int i = blockIdx.x * 256 + threadIdx.x;      // over L*128*128
    if (i >= NUM_LAYERS * 128 * 128) return;
    int l = i >> 14, rem = i & 16383;            // rem = k*128 + n
    int k = rem >> 7, n = rem & 127;
    float w = W2[i];
    unsigned short hs = bf16rne(w);
    float hf = __uint_as_float((unsigned int)hs << 16);
    unsigned short ls = bf16rne(w - hf);
    int c = k >> 4, kk = k & 15;
    size_t base = (((size_t)l * 8 + c) * 2) * 2048;
    W2cm[base + n * 16 + kk]        = (short)hs;
    W2cm[base + 2048 + n * 16 + kk] = (short)ls;
}

// decode sign-magnitude-encoded max + bias -> h
__global__ void k_decode(const unsigned int* __restrict__ enc,
                         const float* __restrict__ b2, float* __restrict__ h)
{
    int i = blockIdx.x * 256 + threadIdx.x;
    if (i >= N_NODES * HIDDEN) return;
    unsigned int u = enc[i];
    unsigned int bits = (u & 0x80000000u) ? (u ^ 0x80000000u) : ~u;
    h[i] = __uint_as_float(bits) + b2[i & (HIDDEN - 1)];
}

__device__ __forceinline__ unsigned int encf(float f)
{
    unsigned int b = __float_as_uint(f);
    return b ^ ((unsigned int)((int)b >> 31) | 0x80000000u);
}

// ---------------- node GEMM: C[M][128] = X[M][K] @ W[K][128] (+bias) ----------------
template <int K>
__global__ __launch_bounds__(256) void k_gemm_nodes(
    const float* __restrict__ X, const float* __restrict__ W,
    const float* __restrict__ bias, float* __restrict__ C, int M)
{
    constexpr int LDX = K + 4;
    __shared__ float Xs[64 * LDX];
    const int t = threadIdx.x;
    const int row0 = blockIdx.x * 64;
    constexpr int F4R = K / 4;
    for (int idx = t; idx < 64 * F4R; idx += 256) {
        int r = idx / F4R, f = idx % F4R;
        int gr = row0 + r;
        float4 v = make_float4(0.f, 0.f, 0.f, 0.f);
        if (gr < M) v = *(const float4*)(X + (size_t)gr * K + 4 * f);
        *(float4*)(Xs + r * LDX + 4 * f) = v;
    }
    __syncthreads();
    const int rg = t >> 4, cg = t & 15;
    float acc[4][8];
#pragma unroll
    for (int i = 0; i < 4; ++i)
#pragma unroll
        for (int j = 0; j < 8; ++j) acc[i][j] = 0.f;

#pragma unroll 8
    for (int k = 0; k < K; ++k) {
        float4 w0 = *(const float4*)(W + k * 128 + cg * 8);
        float4 w1 = *(const float4*)(W + k * 128 + cg * 8 + 4);
        float xs[4];
#pragma unroll
        for (int i = 0; i < 4; ++i) xs[i] = Xs[(rg * 4 + i) * LDX + k];
#pragma unroll
        for (int i = 0; i < 4; ++i) {
            acc[i][0] += xs[i] * w0.x; acc[i][1] += xs[i] * w0.y;
            acc[i][2] += xs[i] * w0.z; acc[i][3] += xs[i] * w0.w;
            acc[i][4] += xs[i] * w1.x; acc[i][5] += xs[i] * w1.y;
            acc[i][6] += xs[i] * w1.z; acc[i][7] += xs[i] * w1.w;
        }
    }
    float b[8];
#pragma unroll
    for (int j = 0; j < 8; ++j) b[j] = 0.f;
    if (bias) {
        float4 b0 = *(const float4*)(bias + cg * 8);
        float4 b1 = *(const float4*)(bias + cg * 8 + 4);
        b[0] = b0.x; b[1] = b0.y; b[2] = b0.z; b[3] = b0.w;
        b[4] = b1.x; b[5] = b1.y; b[6] = b1.z; b[7] = b1.w;
    }
#pragma unroll
    for (int i = 0; i < 4; ++i) {
        int r = row0 + rg * 4 + i;
        if (r < M) {
            float4 o0 = make_float4(acc[i][0] + b[0], acc[i][1] + b[1],
                                    acc[i][2] + b[2], acc[i][3] + b[3]);
            float4 o1 = make_float4(acc[i][4] + b[4], acc[i][5] + b[5],
                                    acc[i][6] + b[6], acc[i][7] + b[7]);
            *(float4*)(C + (size_t)r * 128 + cg * 8) = o0;
            *(float4*)(C + (size_t)r * 128 + cg * 8 + 4) = o1;
        }
    }
}

// ---------------- EdgeConv, MFMA bf16 hi/lo split (the hot one) ----------------
// Block b: 64 dst-sorted edge slots. T = relu(A[dst]+B[src]) split to bf16
// hi/lo in swizzled LDS; m = T @ W2 via 4-term 32x32x16 bf16 MFMA;
// segmented col-max by dst -> atomicMax (monotone-idempotent, partial
// segment flushes are safe).
__global__ __launch_bounds__(256) void k_edge3(
    const float* __restrict__ A, const float* __restrict__ Bm,
    const int* __restrict__ esrc, const int* __restrict__ edst,
    const short* __restrict__ W2l,   // this layer: [8 c][2 h][128 n][16 k] bf16
    unsigned int* __restrict__ enc)
{
    __shared__ __align__(16) short Ts[2][64 * 128];   // [hi/lo][row][k] swizzled, 32 KB
    __shared__ __align__(16) short W2s[2 * 2 * 2048]; // [buf][h][n*16+k], 16 KB
    __shared__ int dsts[EB3];

    const int t = threadIdx.x;
    const int s0 = blockIdx.x * EB3;

    // ---- stage T hi/lo (4 threads per edge slot, 32 k-values each) ----
    {
        const int row = t >> 2;
        const int slot = s0 + row;
        int dst = -1, src = 0;
        if (slot < NT) { dst = edst[slot]; src = esrc[slot]; }
        if ((t & 3) == 0) dsts[row] = dst;
        const int kb = (t & 3) * 32;
        if (dst >= 0) {
            const float* Ar = A + (size_t)dst * HIDDEN + kb;
            const float* Br = Bm + (size_t)src * HIDDEN + kb;
#pragma unroll
            for (int u = 0; u < 4; ++u) {
                float4 a0 = *(const float4*)(Ar + 8 * u);
                float4 a1 = *(const float4*)(Ar + 8 * u + 4);
                float4 b0 = *(const float4*)(Br + 8 * u);
                float4 b1 = *(const float4*)(Br + 8 * u + 4);
                float v[8];
                v[0] = fmaxf(a0.x + b0.x, 0.f); v[1] = fmaxf(a0.y + b0.y, 0.f);
                v[2] = fmaxf(a0.z + b0.z, 0.f); v[3] = fmaxf(a0.w + b0.w, 0.f);
                v[4] = fmaxf(a1.x + b1.x, 0.f); v[5] = fmaxf(a1.y + b1.y, 0.f);
                v[6] = fmaxf(a1.z + b1.z, 0.f); v[7] = fmaxf(a1.w + b1.w, 0.f);
                short8v sh, sl;
#pragma unroll
                for (int j = 0; j < 8; ++j) {
                    unsigned short hs = bf16rne(v[j]);
                    float hf = __uint_as_float((unsigned int)hs << 16);
                    unsigned short ls = bf16rne(v[j] - hf);
                    sh[j] = (short)hs;
                    sl[j] = (short)ls;
                }
                const int ua = (t & 3) * 4 + u;          // 16B unit within row
                const int sw = ua ^ (row & 7);           // XOR swizzle
                *(short8v*)(&Ts[0][row * 128 + sw * 8]) = sh;
                *(short8v*)(&Ts[1][row * 128 + sw * 8]) = sl;
            }
        } else {
            short8v z = {0, 0, 0, 0, 0, 0, 0, 0};
#pragma unroll
            for (int u = 0; u < 4; ++u) {
                const int ua = (t & 3) * 4 + u;
                const int sw = ua ^ (row & 7);
                *(short8v*)(&Ts[0][row * 128 + sw * 8]) = z;
                *(short8v*)(&Ts[1][row * 128 + sw * 8]) = z;
            }
        }
    }

    // ---- stage W2 chunk 0 into buf 0 ----
#pragma unroll
    for (int hsel = 0; hsel < 2; ++hsel) {
        short8v v = *(const short8v*)(W2l + hsel * 2048 + t * 8);
        *(short8v*)(&W2s[hsel * 2048 + t * 8]) = v;
    }
    __syncthreads();

    // ---- MFMA k-loop: 8 chunks of K=16 ----
    const int lane = t & 63;
    const int wv   = t >> 6;
    const int eb   = (wv >> 1) * 32;     // wave's edge-slab base
    const int nb   = (wv & 1) * 64;      // wave's col-slab base (2 tiles of 32)
    const int m    = lane & 31;
    const int kh   = lane >> 5;          // k-half within chunk

    f32x16 acc0 = {0,0,0,0,0,0,0,0,0,0,0,0,0,0,0,0};
    f32x16 acc1 = {0,0,0,0,0,0,0,0,0,0,0,0,0,0,0,0};

    const int arow = eb + m;
    const int abase = arow * 128;
    const int arsw  = (arow & 7);

    for (int c = 0; c < 8; ++c) {
        const int buf = c & 1;
        // prefetch next W2 chunk early (latency hides under MFMAs)
        short8v p0, p1;
        const bool pf = (c < 7);
        if (pf) {
            p0 = *(const short8v*)(W2l + ((c + 1) * 2 + 0) * 2048 + t * 8);
            p1 = *(const short8v*)(W2l + ((c + 1) * 2 + 1) * 2048 + t * 8);
        }
        // A fragments (hi, lo) — swizzled row read
        const int u  = 2 * c + kh;
        const int sw = u ^ arsw;
        short8v ah = *(const short8v*)(&Ts[0][abase + sw * 8]);
        short8v al = *(const short8v*)(&Ts[1][abase + sw * 8]);
        // B fragments for 2 n-tiles (hi, lo each)
        const short* Wb = &W2s[buf * 4096];
        short8v bh0 = *(const short8v*)(Wb +        (nb +      m) * 16 + kh * 8);
        short8v bl0 = *(const short8v*)(Wb + 2048 + (nb +      m) * 16 + kh * 8);
        short8v bh1 = *(const short8v*)(Wb +        (nb + 32 + m) * 16 + kh * 8);
        short8v bl1 = *(const short8v*)(Wb + 2048 + (nb + 32 + m) * 16 + kh * 8);

        acc0 = __builtin_amdgcn_mfma_f32_32x32x16_bf16(ah, bh0, acc0, 0, 0, 0);
        acc0 = __builtin_amdgcn_mfma_f32_32x32x16_bf16(al, bh0, acc0, 0, 0, 0);
        acc0 = __builtin_amdgcn_mfma_f32_32x32x16_bf16(ah, bl0, acc0, 0, 0, 0);
        acc0 = __builtin_amdgcn_mfma_f32_32x32x16_bf16(al, bl0, acc0, 0, 0, 0);
        acc1 = __builtin_amdgcn_mfma_f32_32x32x16_bf16(ah, bh1, acc1, 0, 0, 0);
        acc1 = __builtin_amdgcn_mfma_f32_32x32x16_bf16(al, bh1, acc1, 0, 0, 0);
        acc1 = __builtin_amdgcn_mfma_f32_32x32x16_bf16(ah, bl1, acc1, 0, 0, 0);
        acc1 = __builtin_amdgcn_mfma_f32_32x32x16_bf16(al, bl1, acc1, 0, 0, 0);

        // write prefetched chunk to the other buffer
        if (pf) {
            *(short8v*)(&W2s[(buf ^ 1) * 4096 +        t * 8]) = p0;
            *(short8v*)(&W2s[(buf ^ 1) * 4096 + 2048 + t * 8]) = p1;
        }
        __syncthreads();
    }

    // ---- spill m (f32) into LDS over Ts ----
    float* mf = (float*)&Ts[0][0];       // [64][128] f32 = 32 KB
#pragma unroll 16
    for (int r = 0; r < 16; ++r) {
        const int er = (r & 3) + 8 * (r >> 2) + 4 * kh;
        mf[(eb + er) * 128 + nb +      m] = acc0[r];
        mf[(eb + er) * 128 + nb + 32 + m] = acc1[r];
    }
    __syncthreads();

    // ---- vectorized segmented column max -> atomicMax ----
    if (t < 128) {
        const int cb = (t & 31) * 4;     // 4 consecutive cols
        const int r0 = (t >> 5) * 16;    // 16-edge range
        float4 run = make_float4(-3.4e38f, -3.4e38f, -3.4e38f, -3.4e38f);
        int curd = dsts[r0];
        for (int e = r0; e < r0 + 16; ++e) {
            int d = dsts[e];
            if (d != curd) {
                if (curd >= 0) {
                    unsigned int* ep = &enc[(size_t)curd * HIDDEN + cb];
                    atomicMax(ep + 0, encf(run.x));
                    atomicMax(ep + 1, encf(run.y));
                    atomicMax(ep + 2, encf(run.z));
                    atomicMax(ep + 3, encf(run.w));
                }
                curd = d;
                run = make_float4(-3.4e38f, -3.4e38f, -3.4e38f, -3.4e38f);
            }
            float4 v = *(const float4*)(mf + e * 128 + cb);
            run.x = fmaxf(run.x, v.x); run.y = fmaxf(run.y, v.y);
            run.z = fmaxf(run.z, v.z); run.w = fmaxf(run.w, v.w);
        }
        if (curd >= 0) {
            unsigned int* ep = &enc[(size_t)curd * HIDDEN + cb];
            atomicMax(ep + 0, encf(run.x));
            atomicMax(ep + 1, encf(run.y));
            atomicMax(ep + 2, encf(run.z));
            atomicMax(ep + 3, encf(run.w));
        }
    }
}

// ---------------- launch ----------------
extern "C" void kernel_launch(void* const* d_in, const int* in_sizes, int n_in,
                              void* d_out, int out_size, void* d_ws, size_t ws_size,
                              hipStream_t stream)
{
    const float* x     = (const float*)d_in[0];
    const int*   ei    = (const int*)d_in[1];
    const float* W_emb = (const float*)d_in[2];
    const float* b_emb = (const float*)d_in[3];
    const float* W1    = (const float*)d_in[4];
    const float* b1    = (const float*)d_in[5];
    const float* W2    = (const float*)d_in[6];
    const float* b2    = (const float*)d_in[7];
    const float* W_fc  = (const float*)d_in[8];
    const float* b_fc  = (const float*)d_in[9];
    float* out = (float*)d_out;

    char* p = (char*)d_ws;
    auto alloc = [&](size_t bytes) {
        char* r = p;
        p += (bytes + 255) & ~(size_t)255;
        return r;
    };
    float* h    = (float*)alloc((size_t)N_NODES * HIDDEN * 4);
    float* Ab   = (float*)alloc((size_t)N_NODES * HIDDEN * 4);
    float* Bb   = (float*)alloc((size_t)N_NODES * HIDDEN * 4);
    unsigned int* enc = (unsigned int*)alloc((size_t)N_NODES * HIDDEN * 4);
    float* Wa   = (float*)alloc((size_t)NUM_LAYERS * 16384 * 4);
    float* Wb   = (float*)alloc((size_t)NUM_LAYERS * 16384 * 4);
    short* W2cm = (short*)alloc((size_t)NUM_LAYERS * 8 * 2 * 2048 * 2);
    int* cursor = (int*)alloc(N_NODES * 4);
    int* cnt    = (int*)alloc(N_NODES * 4);
    int* esrc   = (int*)alloc((size_t)NT * 4);
    int* edst   = (int*)alloc((size_t)NT * 4);
    int* srcN   = (int*)alloc((size_t)N_EDGES * 4);
    int* dstN   = (int*)alloc((size_t)N_EDGES * 4);
    int* flag   = (int*)alloc(4);

    const int EBLK = (N_EDGES + 255) / 256;

    k_detect<<<1, 256, 0, stream>>>(ei, flag);
    k_normalize<<<EBLK, 256, 0, stream>>>(ei, flag, srcN, dstN);
    k_zero<<<(N_NODES + 255) / 256, 256, 0, stream>>>(cnt, N_NODES);
    k_count<<<EBLK, 256, 0, stream>>>(dstN, cnt);
    k_scan<<<1, 256, 0, stream>>>(cnt, cursor);
    k_scatter<<<EBLK, 256, 0, stream>>>(srcN, dstN, cursor, esrc, edst);
    k_selfloop<<<(N_NODES + 255) / 256, 256, 0, stream>>>(cursor, esrc, edst);
    k_prepw<<<(NUM_LAYERS * 16384 + 255) / 256, 256, 0, stream>>>(W1, Wa, Wb);
    k_prepw2<<<(NUM_LAYERS * 16384 + 255) / 256, 256, 0, stream>>>(W2, W2cm);

    const int GB  = (N_NODES + 63) / 64;          // 157
    const int EG  = (NT + EB3 - 1) / EB3;         // 10157
    const int NZ  = (N_NODES * HIDDEN + 255) / 256;

    k_gemm_nodes<NODE_DIM><<<GB, 256, 0, stream>>>(x, W_emb, b_emb, h, N_NODES);

    for (int l = 0; l < NUM_LAYERS; ++l) {
        k_gemm_nodes<HIDDEN><<<GB, 256, 0, stream>>>(h, Wa + l * 16384, b1 + l * 128, Ab, N_NODES);
        k_gemm_nodes<HIDDEN><<<GB, 256, 0, stream>>>(h, Wb + l * 16384, nullptr, Bb, N_NODES);
        k_zero<<<NZ, 256, 0, stream>>>((int*)enc, N_NODES * HIDDEN);
        k_edge3<<<EG, 256, 0, stream>>>(Ab, Bb, esrc, edst,
                                        W2cm + (size_t)l * 32768, enc);
        k_decode<<<NZ, 256, 0, stream>>>(enc, b2 + l * 128, h);
    }
    k_gemm_nodes<HIDDEN><<<GB, 256, 0, stream>>>(h, W_fc, b_fc, out, N_NODES);
}

// Round 4
// 783.042 us; speedup vs baseline: 2.1396x; 1.2681x over previous
//
#include <hip/hip_runtime.h>

#define N_NODES 10000
#define N_EDGES 640000
#define NODE_DIM 64
#define HIDDEN 128
#define NUM_LAYERS 4
#define NT (N_EDGES + N_NODES)   // 650000 edge slots incl. self loops
#define EB3 64                   // edge slots per block in k_edge4

typedef __attribute__((ext_vector_type(8))) short short8v;
typedef __attribute__((ext_vector_type(16))) float f32x16;

// ---------------- edge dtype detection / normalization ----------------
__global__ void k_detect(const int* __restrict__ ei, int* __restrict__ flag)
{
    __shared__ int nz;
    if (threadIdx.x == 0) nz = 0;
    __syncthreads();
    int found = 0;
    for (int k = threadIdx.x; k < 2048; k += 256) {
        int pos = 2 * (k * 156) + 1;
        if (ei[pos] != 0) found = 1;
    }
    if (found) atomicOr(&nz, 1);
    __syncthreads();
    if (threadIdx.x == 0) flag[0] = nz;          // 1 = int32 layout, 0 = int64
}

__global__ void k_normalize(const int* __restrict__ ei, const int* __restrict__ flag,
                            int* __restrict__ srcN, int* __restrict__ dstN)
{
    int e = blockIdx.x * 256 + threadIdx.x;
    if (e >= N_EDGES) return;
    if (flag[0]) {
        srcN[e] = ei[e];
        dstN[e] = ei[N_EDGES + e];
    } else {
        srcN[e] = ei[2 * e];
        dstN[e] = ei[2 * (N_EDGES + e)];
    }
}

__global__ void k_zero(int* __restrict__ p, int n)
{
    int i = blockIdx.x * 256 + threadIdx.x;
    if (i < n) p[i] = 0;
}

__global__ void k_count(const int* __restrict__ dstN, int* __restrict__ cnt)
{
    int e = blockIdx.x * 256 + threadIdx.x;
    if (e < N_EDGES) atomicAdd(&cnt[dstN[e]], 1);
}

__global__ void k_scan(const int* __restrict__ cnt, int* __restrict__ cursor)
{
    __shared__ int part[256];
    const int t = threadIdx.x;
    const int CH = (N_NODES + 255) / 256;        // 40
    int lo = t * CH, hi = min(N_NODES, lo + CH);
    int s = 0;
    for (int i = lo; i < hi; ++i) s += cnt[i] + 1;
    part[t] = s;
    __syncthreads();
    for (int off = 1; off < 256; off <<= 1) {
        int v = (t >= off) ? part[t - off] : 0;
        __syncthreads();
        part[t] += v;
        __syncthreads();
    }
    int base = (t == 0) ? 0 : part[t - 1];
    for (int i = lo; i < hi; ++i) {
        cursor[i] = base;
        base += cnt[i] + 1;
    }
}

__global__ void k_scatter(const int* __restrict__ srcN, const int* __restrict__ dstN,
                          int* __restrict__ cursor,
                          int* __restrict__ esrc, int* __restrict__ edst)
{
    int e = blockIdx.x * 256 + threadIdx.x;
    if (e < N_EDGES) {
        int d = dstN[e];
        int pos = atomicAdd(&cursor[d], 1);
        esrc[pos] = srcN[e];
        edst[pos] = d;
    }
}

__global__ void k_selfloop(int* __restrict__ cursor,
                           int* __restrict__ esrc, int* __restrict__ edst)
{
    int n = blockIdx.x * 256 + threadIdx.x;
    if (n < N_NODES) {
        int pos = atomicAdd(&cursor[n], 1);
        esrc[pos] = n;
        edst[pos] = n;
    }
}

// Wa = W1[:,:128,:] - W1[:,128:,:] (x_i side);  Wb = W1[:,128:,:] (x_j side)
__global__ void k_prepw(const float* __restrict__ W1, float* __restrict__ Wa,
                        float* __restrict__ Wb)
{
    int i = blockIdx.x * 256 + threadIdx.x;      // over L*128*128
    if (i >= NUM_LAYERS * 128 * 128) return;
    int l = i >> 14, rem = i & 16383;
    float top = W1[l * 32768 + rem];
    float bot = W1[l * 32768 + 16384 + rem];
    Wa[i] = top - bot;
    Wb[i] = bot;
}

__device__ __forceinline__ unsigned short bf16rne(float f)
{
    unsigned int u = __float_as_uint(f);
    unsigned int r = u + 0x7FFFu + ((u >> 16) & 1u);
    return (unsigned short)(r >> 16);
}

// W2 -> chunk-major transposed hi/lo bf16: W2cm[l][c=k/16][h][n][k%16]
__global__ void k_prepw2(const float* __restrict__ W2, short* __restrict__ W2cm)
{
    int i = blockIdx.x * 256 + threadIdx.x;      // over L*128*128
    if (i >= NUM_LAYERS * 128 * 128) return;
    int l = i >> 14, rem = i & 16383;            // rem = k*128 + n
    int k = rem >> 7, n = rem & 127;
    float w = W2[i];
    unsigned short hs = bf16rne(w);
    float hf = __uint_as_float((unsigned int)hs << 16);
    unsigned short ls = bf16rne(w - hf);
    int c = k >> 4, kk = k & 15;
    size_t base = (((size_t)l * 8 + c) * 2) * 2048;
    W2cm[base + n * 16 + kk]        = (short)hs;
    W2cm[base + 2048 + n * 16 + kk] = (short)ls;
}

// decode sign-magnitude-encoded max + bias -> h; reset enc to 0 for next layer
__global__ void k_decode(unsigned int* __restrict__ enc,
                         const float* __restrict__ b2, float* __restrict__ h)
{
    int i = blockIdx.x * 256 + threadIdx.x;
    if (i >= N_NODES * HIDDEN) return;
    unsigned int u = enc[i];
    enc[i] = 0u;
    unsigned int bits = (u & 0x80000000u) ? (u ^ 0x80000000u) : ~u;
    h[i] = __uint_as_float(bits) + b2[i & (HIDDEN - 1)];
}

__device__ __forceinline__ unsigned int encf(float f)
{
    unsigned int b = __float_as_uint(f);
    return b ^ ((unsigned int)((int)b >> 31) | 0x80000000u);
}

// ---------------- node GEMM: C[M][128] = X[M][K] @ W[K][128] (+bias) ----------------
template <int K>
__global__ __launch_bounds__(256) void k_gemm_nodes(
    const float* __restrict__ X, const float* __restrict__ W,
    const float* __restrict__ bias, float* __restrict__ C, int M)
{
    constexpr int LDX = K + 4;
    __shared__ float Xs[64 * LDX];
    const int t = threadIdx.x;
    const int row0 = blockIdx.x * 64;
    constexpr int F4R = K / 4;
    for (int idx = t; idx < 64 * F4R; idx += 256) {
        int r = idx / F4R, f = idx % F4R;
        int gr = row0 + r;
        float4 v = make_float4(0.f, 0.f, 0.f, 0.f);
        if (gr < M) v = *(const float4*)(X + (size_t)gr * K + 4 * f);
        *(float4*)(Xs + r * LDX + 4 * f) = v;
    }
    __syncthreads();
    const int rg = t >> 4, cg = t & 15;
    float acc[4][8];
#pragma unroll
    for (int i = 0; i < 4; ++i)
#pragma unroll
        for (int j = 0; j < 8; ++j) acc[i][j] = 0.f;

#pragma unroll 8
    for (int k = 0; k < K; ++k) {
        float4 w0 = *(const float4*)(W + k * 128 + cg * 8);
        float4 w1 = *(const float4*)(W + k * 128 + cg * 8 + 4);
        float xs[4];
#pragma unroll
        for (int i = 0; i < 4; ++i) xs[i] = Xs[(rg * 4 + i) * LDX + k];
#pragma unroll
        for (int i = 0; i < 4; ++i) {
            acc[i][0] += xs[i] * w0.x; acc[i][1] += xs[i] * w0.y;
            acc[i][2] += xs[i] * w0.z; acc[i][3] += xs[i] * w0.w;
            acc[i][4] += xs[i] * w1.x; acc[i][5] += xs[i] * w1.y;
            acc[i][6] += xs[i] * w1.z; acc[i][7] += xs[i] * w1.w;
        }
    }
    float b[8];
#pragma unroll
    for (int j = 0; j < 8; ++j) b[j] = 0.f;
    if (bias) {
        float4 b0 = *(const float4*)(bias + cg * 8);
        float4 b1 = *(const float4*)(bias + cg * 8 + 4);
        b[0] = b0.x; b[1] = b0.y; b[2] = b0.z; b[3] = b0.w;
        b[4] = b1.x; b[5] = b1.y; b[6] = b1.z; b[7] = b1.w;
    }
#pragma unroll
    for (int i = 0; i < 4; ++i) {
        int r = row0 + rg * 4 + i;
        if (r < M) {
            float4 o0 = make_float4(acc[i][0] + b[0], acc[i][1] + b[1],
                                    acc[i][2] + b[2], acc[i][3] + b[3]);
            float4 o1 = make_float4(acc[i][4] + b[4], acc[i][5] + b[5],
                                    acc[i][6] + b[6], acc[i][7] + b[7]);
            *(float4*)(C + (size_t)r * 128 + cg * 8) = o0;
            *(float4*)(C + (size_t)r * 128 + cg * 8 + 4) = o1;
        }
    }
}

// ---------------- fused node GEMM: Ab = h@Wa + b1, Bb = h@Wb (shared Xs) ----------------
__global__ __launch_bounds__(256) void k_gemm_ab(
    const float* __restrict__ X, const float* __restrict__ WA,
    const float* __restrict__ WB, const float* __restrict__ bias,
    float* __restrict__ CA, float* __restrict__ CB, int M)
{
    __shared__ float Xs[64 * 132];
    const int t = threadIdx.x;
    const int row0 = blockIdx.x * 64;
    for (int idx = t; idx < 64 * 32; idx += 256) {
        int r = idx >> 5, f = idx & 31;
        int gr = row0 + r;
        float4 v = make_float4(0.f, 0.f, 0.f, 0.f);
        if (gr < M) v = *(const float4*)(X + (size_t)gr * 128 + 4 * f);
        *(float4*)(Xs + r * 132 + 4 * f) = v;
    }
    __syncthreads();
    const int rg = t >> 4, cg = t & 15;
    float accA[4][8], accB[4][8];
#pragma unroll
    for (int i = 0; i < 4; ++i)
#pragma unroll
        for (int j = 0; j < 8; ++j) { accA[i][j] = 0.f; accB[i][j] = 0.f; }

#pragma unroll 4
    for (int k = 0; k < 128; ++k) {
        float4 wa0 = *(const float4*)(WA + k * 128 + cg * 8);
        float4 wa1 = *(const float4*)(WA + k * 128 + cg * 8 + 4);
        float4 wb0 = *(const float4*)(WB + k * 128 + cg * 8);
        float4 wb1 = *(const float4*)(WB + k * 128 + cg * 8 + 4);
        float xs[4];
#pragma unroll
        for (int i = 0; i < 4; ++i) xs[i] = Xs[(rg * 4 + i) * 132 + k];
#pragma unroll
        for (int i = 0; i < 4; ++i) {
            accA[i][0] += xs[i] * wa0.x; accA[i][1] += xs[i] * wa0.y;
            accA[i][2] += xs[i] * wa0.z; accA[i][3] += xs[i] * wa0.w;
            accA[i][4] += xs[i] * wa1.x; accA[i][5] += xs[i] * wa1.y;
            accA[i][6] += xs[i] * wa1.z; accA[i][7] += xs[i] * wa1.w;
            accB[i][0] += xs[i] * wb0.x; accB[i][1] += xs[i] * wb0.y;
            accB[i][2] += xs[i] * wb0.z; accB[i][3] += xs[i] * wb0.w;
            accB[i][4] += xs[i] * wb1.x; accB[i][5] += xs[i] * wb1.y;
            accB[i][6] += xs[i] * wb1.z; accB[i][7] += xs[i] * wb1.w;
        }
    }
    float4 b0 = *(const float4*)(bias + cg * 8);
    float4 b1 = *(const float4*)(bias + cg * 8 + 4);
#pragma unroll
    for (int i = 0; i < 4; ++i) {
        int r = row0 + rg * 4 + i;
        if (r < M) {
            *(float4*)(CA + (size_t)r * 128 + cg * 8) =
                make_float4(accA[i][0] + b0.x, accA[i][1] + b0.y,
                            accA[i][2] + b0.z, accA[i][3] + b0.w);
            *(float4*)(CA + (size_t)r * 128 + cg * 8 + 4) =
                make_float4(accA[i][4] + b1.x, accA[i][5] + b1.y,
                            accA[i][6] + b1.z, accA[i][7] + b1.w);
            *(float4*)(CB + (size_t)r * 128 + cg * 8) =
                make_float4(accB[i][0], accB[i][1], accB[i][2], accB[i][3]);
            *(float4*)(CB + (size_t)r * 128 + cg * 8 + 4) =
                make_float4(accB[i][4], accB[i][5], accB[i][6], accB[i][7]);
        }
    }
}

// ---------------- EdgeConv, MFMA 3-term hi/lo, barrier-free k-loop ----------------
// Block: 64 dst-sorted edge slots. T = relu(A[dst]+B[src]) -> bf16 hi/lo in
// swizzled LDS (once). 4 waves, wave wv owns col-tile [wv*32, wv*32+32) and
// BOTH 32-edge slabs. B-fragments stream from global W2cm into registers
// (prefetch 1 chunk ahead); zero barriers / zero LDS B-traffic in the k-loop.
// Segmented col-max computed straight from accumulator regs -> atomicMax.
__global__ __launch_bounds__(256) void k_edge4(
    const float* __restrict__ A, const float* __restrict__ Bm,
    const int* __restrict__ esrc, const int* __restrict__ edst,
    const short* __restrict__ W2l,   // this layer: [8 c][2 h][128 n][16 k] bf16
    unsigned int* __restrict__ enc)
{
    __shared__ __align__(16) short Ts[2][64 * 128];   // [hi/lo][row][k] swizzled, 32 KB
    __shared__ int dsts[EB3];

    const int t = threadIdx.x;
    const int s0 = blockIdx.x * EB3;

    // ---- stage T hi/lo (4 threads per edge slot, 32 k-values each) ----
    {
        const int row = t >> 2;
        const int slot = s0 + row;
        int dst = -1, src = 0;
        if (slot < NT) { dst = edst[slot]; src = esrc[slot]; }
        if ((t & 3) == 0) dsts[row] = dst;
        const int kb = (t & 3) * 32;
        if (dst >= 0) {
            const float* Ar = A + (size_t)dst * HIDDEN + kb;
            const float* Br = Bm + (size_t)src * HIDDEN + kb;
#pragma unroll
            for (int u = 0; u < 4; ++u) {
                float4 a0 = *(const float4*)(Ar + 8 * u);
                float4 a1 = *(const float4*)(Ar + 8 * u + 4);
                float4 b0 = *(const float4*)(Br + 8 * u);
                float4 b1 = *(const float4*)(Br + 8 * u + 4);
                float v[8];
                v[0] = fmaxf(a0.x + b0.x, 0.f); v[1] = fmaxf(a0.y + b0.y, 0.f);
                v[2] = fmaxf(a0.z + b0.z, 0.f); v[3] = fmaxf(a0.w + b0.w, 0.f);
                v[4] = fmaxf(a1.x + b1.x, 0.f); v[5] = fmaxf(a1.y + b1.y, 0.f);
                v[6] = fmaxf(a1.z + b1.z, 0.f); v[7] = fmaxf(a1.w + b1.w, 0.f);
                short8v sh, sl;
#pragma unroll
                for (int j = 0; j < 8; ++j) {
                    unsigned short hs = bf16rne(v[j]);
                    float hf = __uint_as_float((unsigned int)hs << 16);
                    unsigned short ls = bf16rne(v[j] - hf);
                    sh[j] = (short)hs;
                    sl[j] = (short)ls;
                }
                const int ua = (t & 3) * 4 + u;          // 16B unit within row
                const int sw = ua ^ (row & 7);           // XOR swizzle
                *(short8v*)(&Ts[0][row * 128 + sw * 8]) = sh;
                *(short8v*)(&Ts[1][row * 128 + sw * 8]) = sl;
            }
        } else {
            short8v z = {0, 0, 0, 0, 0, 0, 0, 0};
#pragma unroll
            for (int u = 0; u < 4; ++u) {
                const int ua = (t & 3) * 4 + u;
                const int sw = ua ^ (row & 7);
                *(short8v*)(&Ts[0][row * 128 + sw * 8]) = z;
                *(short8v*)(&Ts[1][row * 128 + sw * 8]) = z;
            }
        }
    }
    __syncthreads();   // the only block barrier

    const int lane = t & 63;
    const int wv   = t >> 6;
    const int nb   = wv * 32;            // wave's 32-col tile
    const int m    = lane & 31;
    const int kh   = lane >> 5;          // k-half within a 16-chunk

    f32x16 acc0 = {0,0,0,0,0,0,0,0,0,0,0,0,0,0,0,0};   // edge slab 0 (rows 0-31)
    f32x16 acc1 = {0,0,0,0,0,0,0,0,0,0,0,0,0,0,0,0};   // edge slab 1 (rows 32-63)

    const int ab0 = m * 128;             // Ts base, slab-0 row (shorts)
    const int ab1 = (32 + m) * 128;      // slab-1 row; (32+m)&7 == m&7
    const int msw = m & 7;

    const short* Wp = W2l + (size_t)(nb + m) * 16 + kh * 8;

    short8v bh = *(const short8v*)(Wp);
    short8v bl = *(const short8v*)(Wp + 2048);

#pragma unroll
    for (int c = 0; c < 8; ++c) {
        short8v nh, nl;
        if (c < 7) {                     // prefetch next chunk's B-frags
            nh = *(const short8v*)(Wp + (size_t)(c + 1) * 4096);
            nl = *(const short8v*)(Wp + (size_t)(c + 1) * 4096 + 2048);
        }
        const int sw8 = ((2 * c + kh) ^ msw) * 8;
        short8v ah0 = *(const short8v*)(&Ts[0][ab0 + sw8]);
        short8v al0 = *(const short8v*)(&Ts[1][ab0 + sw8]);
        short8v ah1 = *(const short8v*)(&Ts[0][ab1 + sw8]);
        short8v al1 = *(const short8v*)(&Ts[1][ab1 + sw8]);

        acc0 = __builtin_amdgcn_mfma_f32_32x32x16_bf16(ah0, bh, acc0, 0, 0, 0);
        acc0 = __builtin_amdgcn_mfma_f32_32x32x16_bf16(al0, bh, acc0, 0, 0, 0);
        acc0 = __builtin_amdgcn_mfma_f32_32x32x16_bf16(ah0, bl, acc0, 0, 0, 0);
        acc1 = __builtin_amdgcn_mfma_f32_32x32x16_bf16(ah1, bh, acc1, 0, 0, 0);
        acc1 = __builtin_amdgcn_mfma_f32_32x32x16_bf16(al1, bh, acc1, 0, 0, 0);
        acc1 = __builtin_amdgcn_mfma_f32_32x32x16_bf16(ah1, bl, acc1, 0, 0, 0);

        if (c < 7) { bh = nh; bl = nl; }
    }

    // ---- segmented col-max straight from accumulators -> atomicMax ----
    // D layout: col = lane&31 (our n), row er = (r&3)+8*(r>>2)+4*kh, monotone
    // in r; dsts sorted by slot => running-segment walk per lane. d is uniform
    // across each 32-lane half => coalesced atomics over 32 consecutive cols.
    const int col = nb + m;
    {
        float run = -3.4e38f;
        int curd = dsts[4 * kh];
#pragma unroll
        for (int r = 0; r < 16; ++r) {
            const int er = (r & 3) + 8 * (r >> 2) + 4 * kh;
            int d = dsts[er];
            if (d != curd) {
                if (curd >= 0)
                    atomicMax(&enc[(size_t)curd * HIDDEN + col], encf(run));
                curd = d;
                run = -3.4e38f;
            }
            run = fmaxf(run, acc0[r]);
        }
        if (curd >= 0)
            atomicMax(&enc[(size_t)curd * HIDDEN + col], encf(run));
    }
    {
        float run = -3.4e38f;
        int curd = dsts[32 + 4 * kh];
#pragma unroll
        for (int r = 0; r < 16; ++r) {
            const int er = 32 + (r & 3) + 8 * (r >> 2) + 4 * kh;
            int d = dsts[er];
            if (d != curd) {
                if (curd >= 0)
                    atomicMax(&enc[(size_t)curd * HIDDEN + col], encf(run));
                curd = d;
                run = -3.4e38f;
            }
            run = fmaxf(run, acc1[r]);
        }
        if (curd >= 0)
            atomicMax(&enc[(size_t)curd * HIDDEN + col], encf(run));
    }
}

// ---------------- launch ----------------
extern "C" void kernel_launch(void* const* d_in, const int* in_sizes, int n_in,
                              void* d_out, int out_size, void* d_ws, size_t ws_size,
                              hipStream_t stream)
{
    const float* x     = (const float*)d_in[0];
    const int*   ei    = (const int*)d_in[1];
    const float* W_emb = (const float*)d_in[2];
    const float* b_emb = (const float*)d_in[3];
    const float* W1    = (const float*)d_in[4];
    const float* b1    = (const float*)d_in[5];
    const float* W2    = (const float*)d_in[6];
    const float* b2    = (const float*)d_in[7];
    const float* W_fc  = (const float*)d_in[8];
    const float* b_fc  = (const float*)d_in[9];
    float* out = (float*)d_out;

    char* p = (char*)d_ws;
    auto alloc = [&](size_t bytes) {
        char* r = p;
        p += (bytes + 255) & ~(size_t)255;
        return r;
    };
    float* h    = (float*)alloc((size_t)N_NODES * HIDDEN * 4);
    float* Ab   = (float*)alloc((size_t)N_NODES * HIDDEN * 4);
    float* Bb   = (float*)alloc((size_t)N_NODES * HIDDEN * 4);
    unsigned int* enc = (unsigned int*)alloc((size_t)N_NODES * HIDDEN * 4);
    float* Wa   = (float*)alloc((size_t)NUM_LAYERS * 16384 * 4);
    float* Wb   = (float*)alloc((size_t)NUM_LAYERS * 16384 * 4);
    short* W2cm = (short*)alloc((size_t)NUM_LAYERS * 8 * 2 * 2048 * 2);
    int* cursor = (int*)alloc(N_NODES * 4);
    int* cnt    = (int*)alloc(N_NODES * 4);
    int* esrc   = (int*)alloc((size_t)NT * 4);
    int* edst   = (int*)alloc((size_t)NT * 4);
    int* srcN   = (int*)alloc((size_t)N_EDGES * 4);
    int* dstN   = (int*)alloc((size_t)N_EDGES * 4);
    int* flag   = (int*)alloc(4);

    const int EBLK = (N_EDGES + 255) / 256;

    k_detect<<<1, 256, 0, stream>>>(ei, flag);
    k_normalize<<<EBLK, 256, 0, stream>>>(ei, flag, srcN, dstN);
    k_zero<<<(N_NODES + 255) / 256, 256, 0, stream>>>(cnt, N_NODES);
    k_count<<<EBLK, 256, 0, stream>>>(dstN, cnt);
    k_scan<<<1, 256, 0, stream>>>(cnt, cursor);
    k_scatter<<<EBLK, 256, 0, stream>>>(srcN, dstN, cursor, esrc, edst);
    k_selfloop<<<(N_NODES + 255) / 256, 256, 0, stream>>>(cursor, esrc, edst);
    k_prepw<<<(NUM_LAYERS * 16384 + 255) / 256, 256, 0, stream>>>(W1, Wa, Wb);
    k_prepw2<<<(NUM_LAYERS * 16384 + 255) / 256, 256, 0, stream>>>(W2, W2cm);

    const int GB  = (N_NODES + 63) / 64;          // 157
    const int EG  = (NT + EB3 - 1) / EB3;         // 10157
    const int NZ  = (N_NODES * HIDDEN + 255) / 256;

    k_zero<<<NZ, 256, 0, stream>>>((int*)enc, N_NODES * HIDDEN);   // once; k_decode re-zeros
    k_gemm_nodes<NODE_DIM><<<GB, 256, 0, stream>>>(x, W_emb, b_emb, h, N_NODES);

    for (int l = 0; l < NUM_LAYERS; ++l) {
        k_gemm_ab<<<GB, 256, 0, stream>>>(h, Wa + l * 16384, Wb + l * 16384,
                                          b1 + l * 128, Ab, Bb, N_NODES);
        k_edge4<<<EG, 256, 0, stream>>>(Ab, Bb, esrc, edst,
                                        W2cm + (size_t)l * 32768, enc);
        k_decode<<<NZ, 256, 0, stream>>>(enc, b2 + l * 128, h);
    }
    k_gemm_nodes<HIDDEN><<<GB, 256, 0, stream>>>(h, W_fc, b_fc, out, N_NODES);
}

// Round 5
// 779.990 us; speedup vs baseline: 2.1480x; 1.0039x over previous
//
#include <hip/hip_runtime.h>

#define N_NODES 10000
#define N_EDGES 640000
#define NODE_DIM 64
#define HIDDEN 128
#define NUM_LAYERS 4
#define NT (N_EDGES + N_NODES)   // 650000 edge slots incl. self loops
#define EB3 64                   // edge slots per block in k_edge5

typedef __attribute__((ext_vector_type(8))) short short8v;
typedef __attribute__((ext_vector_type(16))) float f32x16;

// ---------------- edge dtype detection / normalization ----------------
__global__ void k_detect(const int* __restrict__ ei, int* __restrict__ flag)
{
    __shared__ int nz;
    if (threadIdx.x == 0) nz = 0;
    __syncthreads();
    int found = 0;
    for (int k = threadIdx.x; k < 2048; k += 256) {
        int pos = 2 * (k * 156) + 1;
        if (ei[pos] != 0) found = 1;
    }
    if (found) atomicOr(&nz, 1);
    __syncthreads();
    if (threadIdx.x == 0) flag[0] = nz;          // 1 = int32 layout, 0 = int64
}

__global__ void k_normalize(const int* __restrict__ ei, const int* __restrict__ flag,
                            int* __restrict__ srcN, int* __restrict__ dstN)
{
    int e = blockIdx.x * 256 + threadIdx.x;
    if (e >= N_EDGES) return;
    if (flag[0]) {
        srcN[e] = ei[e];
        dstN[e] = ei[N_EDGES + e];
    } else {
        srcN[e] = ei[2 * e];
        dstN[e] = ei[2 * (N_EDGES + e)];
    }
}

__global__ void k_zero(int* __restrict__ p, int n)
{
    int i = blockIdx.x * 256 + threadIdx.x;
    if (i < n) p[i] = 0;
}

__global__ void k_count(const int* __restrict__ dstN, int* __restrict__ cnt)
{
    int e = blockIdx.x * 256 + threadIdx.x;
    if (e < N_EDGES) atomicAdd(&cnt[dstN[e]], 1);
}

__global__ void k_scan(const int* __restrict__ cnt, int* __restrict__ cursor)
{
    __shared__ int part[256];
    const int t = threadIdx.x;
    const int CH = (N_NODES + 255) / 256;        // 40
    int lo = t * CH, hi = min(N_NODES, lo + CH);
    int s = 0;
    for (int i = lo; i < hi; ++i) s += cnt[i] + 1;
    part[t] = s;
    __syncthreads();
    for (int off = 1; off < 256; off <<= 1) {
        int v = (t >= off) ? part[t - off] : 0;
        __syncthreads();
        part[t] += v;
        __syncthreads();
    }
    int base = (t == 0) ? 0 : part[t - 1];
    for (int i = lo; i < hi; ++i) {
        cursor[i] = base;
        base += cnt[i] + 1;
    }
}

__global__ void k_scatter(const int* __restrict__ srcN, const int* __restrict__ dstN,
                          int* __restrict__ cursor,
                          int* __restrict__ esrc, int* __restrict__ edst)
{
    int e = blockIdx.x * 256 + threadIdx.x;
    if (e < N_EDGES) {
        int d = dstN[e];
        int pos = atomicAdd(&cursor[d], 1);
        esrc[pos] = srcN[e];
        edst[pos] = d;
    }
}

__global__ void k_selfloop(int* __restrict__ cursor,
                           int* __restrict__ esrc, int* __restrict__ edst)
{
    int n = blockIdx.x * 256 + threadIdx.x;
    if (n < N_NODES) {
        int pos = atomicAdd(&cursor[n], 1);
        esrc[pos] = n;
        edst[pos] = n;
    }
}

// Wa = W1[:,:128,:] - W1[:,128:,:] (x_i side);  Wb = W1[:,128:,:] (x_j side)
__global__ void k_prepw(const float* __restrict__ W1, float* __restrict__ Wa,
                        float* __restrict__ Wb)
{
    int i = blockIdx.x * 256 + threadIdx.x;      // over L*128*128
    if (i >= NUM_LAYERS * 128 * 128) return;
    int l = i >> 14, rem = i & 16383;
    float top = W1[l * 32768 + rem];
    float bot = W1[l * 32768 + 16384 + rem];
    Wa[i] = top - bot;
    Wb[i] = bot;
}

__device__ __forceinline__ unsigned short bf16rne(float f)
{
    unsigned int u = __float_as_uint(f);
    unsigned int r = u + 0x7FFFu + ((u >> 16) & 1u);
    return (unsigned short)(r >> 16);
}

// W2 -> chunk-major transposed hi/lo bf16: W2cm[l][c=k/16][h][n][k%16]
__global__ void k_prepw2(const float* __restrict__ W2, short* __restrict__ W2cm)
{
    int i = blockIdx.x * 256 + threadIdx.x;      // over L*128*128
    if (i >= NUM_LAYERS * 128 * 128) return;
    int l = i >> 14, rem = i & 16383;            // rem = k*128 + n
    int k = rem >> 7, n = rem & 127;
    float w = W2[i];
    unsigned short hs = bf16rne(w);
    float hf = __uint_as_float((unsigned int)hs << 16);
    unsigned short ls = bf16rne(w - hf);
    int c = k >> 4, kk = k & 15;
    size_t base = (((size_t)l * 8 + c) * 2) * 2048;
    W2cm[base + n * 16 + kk]        = (short)hs;
    W2cm[base + 2048 + n * 16 + kk] = (short)ls;
}

// decode sign-magnitude-encoded max + bias -> h; reset enc to 0 for next layer
__global__ void k_decode(unsigned int* __restrict__ enc,
                         const float* __restrict__ b2, float* __restrict__ h)
{
    int i = blockIdx.x * 256 + threadIdx.x;
    if (i >= N_NODES * HIDDEN) return;
    unsigned int u = enc[i];
    enc[i] = 0u;
    unsigned int bits = (u & 0x80000000u) ? (u ^ 0x80000000u) : ~u;
    h[i] = __uint_as_float(bits) + b2[i & (HIDDEN - 1)];
}

__device__ __forceinline__ unsigned int encf(float f)
{
    unsigned int b = __float_as_uint(f);
    return b ^ ((unsigned int)((int)b >> 31) | 0x80000000u);
}

// ---------------- node GEMM: C[M][128] = X[M][K] @ W[K][128] (+bias) ----------------
template <int K>
__global__ __launch_bounds__(256) void k_gemm_nodes(
    const float* __restrict__ X, const float* __restrict__ W,
    const float* __restrict__ bias, float* __restrict__ C, int M)
{
    constexpr int LDX = K + 4;
    __shared__ float Xs[64 * LDX];
    const int t = threadIdx.x;
    const int row0 = blockIdx.x * 64;
    constexpr int F4R = K / 4;
    for (int idx = t; idx < 64 * F4R; idx += 256) {
        int r = idx / F4R, f = idx % F4R;
        int gr = row0 + r;
        float4 v = make_float4(0.f, 0.f, 0.f, 0.f);
        if (gr < M) v = *(const float4*)(X + (size_t)gr * K + 4 * f);
        *(float4*)(Xs + r * LDX + 4 * f) = v;
    }
    __syncthreads();
    const int rg = t >> 4, cg = t & 15;
    float acc[4][8];
#pragma unroll
    for (int i = 0; i < 4; ++i)
#pragma unroll
        for (int j = 0; j < 8; ++j) acc[i][j] = 0.f;

#pragma unroll 8
    for (int k = 0; k < K; ++k) {
        float4 w0 = *(const float4*)(W + k * 128 + cg * 8);
        float4 w1 = *(const float4*)(W + k * 128 + cg * 8 + 4);
        float xs[4];
#pragma unroll
        for (int i = 0; i < 4; ++i) xs[i] = Xs[(rg * 4 + i) * LDX + k];
#pragma unroll
        for (int i = 0; i < 4; ++i) {
            acc[i][0] += xs[i] * w0.x; acc[i][1] += xs[i] * w0.y;
            acc[i][2] += xs[i] * w0.z; acc[i][3] += xs[i] * w0.w;
            acc[i][4] += xs[i] * w1.x; acc[i][5] += xs[i] * w1.y;
            acc[i][6] += xs[i] * w1.z; acc[i][7] += xs[i] * w1.w;
        }
    }
    float b[8];
#pragma unroll
    for (int j = 0; j < 8; ++j) b[j] = 0.f;
    if (bias) {
        float4 b0 = *(const float4*)(bias + cg * 8);
        float4 b1 = *(const float4*)(bias + cg * 8 + 4);
        b[0] = b0.x; b[1] = b0.y; b[2] = b0.z; b[3] = b0.w;
        b[4] = b1.x; b[5] = b1.y; b[6] = b1.z; b[7] = b1.w;
    }
#pragma unroll
    for (int i = 0; i < 4; ++i) {
        int r = row0 + rg * 4 + i;
        if (r < M) {
            float4 o0 = make_float4(acc[i][0] + b[0], acc[i][1] + b[1],
                                    acc[i][2] + b[2], acc[i][3] + b[3]);
            float4 o1 = make_float4(acc[i][4] + b[4], acc[i][5] + b[5],
                                    acc[i][6] + b[6], acc[i][7] + b[7]);
            *(float4*)(C + (size_t)r * 128 + cg * 8) = o0;
            *(float4*)(C + (size_t)r * 128 + cg * 8 + 4) = o1;
        }
    }
}

// ---------------- fused node GEMM: Ab = h@Wa + b1, Bb = h@Wb (shared Xs) ----------------
__global__ __launch_bounds__(256) void k_gemm_ab(
    const float* __restrict__ X, const float* __restrict__ WA,
    const float* __restrict__ WB, const float* __restrict__ bias,
    float* __restrict__ CA, float* __restrict__ CB, int M)
{
    __shared__ float Xs[64 * 132];
    const int t = threadIdx.x;
    const int row0 = blockIdx.x * 64;
    for (int idx = t; idx < 64 * 32; idx += 256) {
        int r = idx >> 5, f = idx & 31;
        int gr = row0 + r;
        float4 v = make_float4(0.f, 0.f, 0.f, 0.f);
        if (gr < M) v = *(const float4*)(X + (size_t)gr * 128 + 4 * f);
        *(float4*)(Xs + r * 132 + 4 * f) = v;
    }
    __syncthreads();
    const int rg = t >> 4, cg = t & 15;
    float accA[4][8], accB[4][8];
#pragma unroll
    for (int i = 0; i < 4; ++i)
#pragma unroll
        for (int j = 0; j < 8; ++j) { accA[i][j] = 0.f; accB[i][j] = 0.f; }

#pragma unroll 4
    for (int k = 0; k < 128; ++k) {
        float4 wa0 = *(const float4*)(WA + k * 128 + cg * 8);
        float4 wa1 = *(const float4*)(WA + k * 128 + cg * 8 + 4);
        float4 wb0 = *(const float4*)(WB + k * 128 + cg * 8);
        float4 wb1 = *(const float4*)(WB + k * 128 + cg * 8 + 4);
        float xs[4];
#pragma unroll
        for (int i = 0; i < 4; ++i) xs[i] = Xs[(rg * 4 + i) * 132 + k];
#pragma unroll
        for (int i = 0; i < 4; ++i) {
            accA[i][0] += xs[i] * wa0.x; accA[i][1] += xs[i] * wa0.y;
            accA[i][2] += xs[i] * wa0.z; accA[i][3] += xs[i] * wa0.w;
            accA[i][4] += xs[i] * wa1.x; accA[i][5] += xs[i] * wa1.y;
            accA[i][6] += xs[i] * wa1.z; accA[i][7] += xs[i] * wa1.w;
            accB[i][0] += xs[i] * wb0.x; accB[i][1] += xs[i] * wb0.y;
            accB[i][2] += xs[i] * wb0.z; accB[i][3] += xs[i] * wb0.w;
            accB[i][4] += xs[i] * wb1.x; accB[i][5] += xs[i] * wb1.y;
            accB[i][6] += xs[i] * wb1.z; accB[i][7] += xs[i] * wb1.w;
        }
    }
    float4 b0 = *(const float4*)(bias + cg * 8);
    float4 b1 = *(const float4*)(bias + cg * 8 + 4);
#pragma unroll
    for (int i = 0; i < 4; ++i) {
        int r = row0 + rg * 4 + i;
        if (r < M) {
            *(float4*)(CA + (size_t)r * 128 + cg * 8) =
                make_float4(accA[i][0] + b0.x, accA[i][1] + b0.y,
                            accA[i][2] + b0.z, accA[i][3] + b0.w);
            *(float4*)(CA + (size_t)r * 128 + cg * 8 + 4) =
                make_float4(accA[i][4] + b1.x, accA[i][5] + b1.y,
                            accA[i][6] + b1.z, accA[i][7] + b1.w);
            *(float4*)(CB + (size_t)r * 128 + cg * 8) =
                make_float4(accB[i][0], accB[i][1], accB[i][2], accB[i][3]);
            *(float4*)(CB + (size_t)r * 128 + cg * 8 + 4) =
                make_float4(accB[i][4], accB[i][5], accB[i][6], accB[i][7]);
        }
    }
}

// ---------------- EdgeConv, MFMA 3-term, fragment-linear LDS ----------------
// Ts holds A-fragments in MFMA fragment order:
//   unit idx = ((p*2+s)*8 + c)*64 + (kh*32 + m)   (16B units; p=plane hi/lo,
//   s=edge slab, c=k-chunk, lane l = kh*32+m)
//   stored at (idx ^ c) to spread bank groups (reads AND writes 2-way = free).
// Wave wv owns col-tile [wv*32, wv*32+32), both slabs. B streams from global
// (prefetch +1 chunk); A-frags prefetched +1 chunk from LDS under the MFMAs.
__global__ __launch_bounds__(256, 4) void k_edge5(
    const float* __restrict__ A, const float* __restrict__ Bm,
    const int* __restrict__ esrc, const int* __restrict__ edst,
    const short* __restrict__ W2l,   // this layer: [8 c][2 h][128 n][16 k] bf16
    unsigned int* __restrict__ enc)
{
    __shared__ __align__(16) short Ts[2048 * 8];   // 32 KB, fragment-linear
    __shared__ int dsts[EB3];

    const int t = threadIdx.x;
    const int s0 = blockIdx.x * EB3;

    // ---- stage T hi/lo (4 threads per edge slot, 32 k-values each) ----
    {
        const int row = t >> 2;          // edge slot within block
        const int q   = t & 3;           // k-quarter (32 values)
        const int slot = s0 + row;
        int dst = -1, src = 0;
        if (slot < NT) { dst = edst[slot]; src = esrc[slot]; }
        if (q == 0) dsts[row] = dst;
        const int sfrag = row >> 5;      // slab
        const int mrow  = row & 31;      // m within slab
        const float* Ar = A + (size_t)((dst >= 0) ? dst : 0) * HIDDEN;
        const float* Br = Bm + (size_t)src * HIDDEN;
#pragma unroll
        for (int cc = 0; cc < 2; ++cc) {
#pragma unroll
            for (int kh = 0; kh < 2; ++kh) {
                short8v sh = {0,0,0,0,0,0,0,0}, sl = {0,0,0,0,0,0,0,0};
                if (dst >= 0) {
                    const int kb = q * 32 + cc * 16 + kh * 8;
                    float4 a0 = *(const float4*)(Ar + kb);
                    float4 a1 = *(const float4*)(Ar + kb + 4);
                    float4 b0 = *(const float4*)(Br + kb);
                    float4 b1 = *(const float4*)(Br + kb + 4);
                    float f[8];
                    f[0] = fmaxf(a0.x + b0.x, 0.f); f[1] = fmaxf(a0.y + b0.y, 0.f);
                    f[2] = fmaxf(a0.z + b0.z, 0.f); f[3] = fmaxf(a0.w + b0.w, 0.f);
                    f[4] = fmaxf(a1.x + b1.x, 0.f); f[5] = fmaxf(a1.y + b1.y, 0.f);
                    f[6] = fmaxf(a1.z + b1.z, 0.f); f[7] = fmaxf(a1.w + b1.w, 0.f);
#pragma unroll
                    for (int j = 0; j < 8; ++j) {
                        unsigned short hs = bf16rne(f[j]);
                        float hf = __uint_as_float((unsigned int)hs << 16);
                        sh[j] = (short)hs;
                        sl[j] = (short)bf16rne(f[j] - hf);
                    }
                }
                const int c  = 2 * q + cc;
                const int ih = ((sfrag)     * 8 + c) * 64 + kh * 32 + mrow;  // p=0
                const int il = ((2 + sfrag) * 8 + c) * 64 + kh * 32 + mrow;  // p=1
                *(short8v*)(&Ts[(size_t)(ih ^ c) * 8]) = sh;
                *(short8v*)(&Ts[(size_t)(il ^ c) * 8]) = sl;
            }
        }
    }
    __syncthreads();   // the only block barrier

    const int lane = t & 63;
    const int wv   = t >> 6;
    const int nb   = wv * 32;            // wave's 32-col tile
    const int m    = lane & 31;
    const int kh   = lane >> 5;

    f32x16 acc0 = {0,0,0,0,0,0,0,0,0,0,0,0,0,0,0,0};   // slab 0 (rows 0-31)
    f32x16 acc1 = {0,0,0,0,0,0,0,0,0,0,0,0,0,0,0,0};   // slab 1 (rows 32-63)

    // A-frag base unit indices (chunk 0): plane p, slab s -> ((p*2+s)*8)*64 + lane
    const int b00 = 0 * 512 + lane;      // p0 s0
    const int b01 = 1 * 512 + lane;      // p0 s1
    const int b10 = 2 * 512 + lane;      // p1 s0
    const int b11 = 3 * 512 + lane;      // p1 s1

    const short* Wp = W2l + (size_t)(nb + m) * 16 + kh * 8;

    // chunk-0 loads (idx ^ 0 = idx)
    short8v bh  = *(const short8v*)(Wp);
    short8v bl  = *(const short8v*)(Wp + 2048);
    short8v ah0 = *(const short8v*)(&Ts[(size_t)b00 * 8]);
    short8v al0 = *(const short8v*)(&Ts[(size_t)b10 * 8]);
    short8v ah1 = *(const short8v*)(&Ts[(size_t)b01 * 8]);
    short8v al1 = *(const short8v*)(&Ts[(size_t)b11 * 8]);

#pragma unroll
    for (int c = 0; c < 8; ++c) {
        short8v nbh, nbl, nh0, nl0, nh1, nl1;
        if (c < 7) {                     // prefetch chunk c+1 (B global, A LDS)
            const int cn = c + 1;
            nbh = *(const short8v*)(Wp + (size_t)cn * 4096);
            nbl = *(const short8v*)(Wp + (size_t)cn * 4096 + 2048);
            nh0 = *(const short8v*)(&Ts[(size_t)((b00 + cn * 64) ^ cn) * 8]);
            nl0 = *(const short8v*)(&Ts[(size_t)((b10 + cn * 64) ^ cn) * 8]);
            nh1 = *(const short8v*)(&Ts[(size_t)((b01 + cn * 64) ^ cn) * 8]);
            nl1 = *(const short8v*)(&Ts[(size_t)((b11 + cn * 64) ^ cn) * 8]);
        }
        acc0 = __builtin_amdgcn_mfma_f32_32x32x16_bf16(ah0, bh, acc0, 0, 0, 0);
        acc0 = __builtin_amdgcn_mfma_f32_32x32x16_bf16(al0, bh, acc0, 0, 0, 0);
        acc0 = __builtin_amdgcn_mfma_f32_32x32x16_bf16(ah0, bl, acc0, 0, 0, 0);
        acc1 = __builtin_amdgcn_mfma_f32_32x32x16_bf16(ah1, bh, acc1, 0, 0, 0);
        acc1 = __builtin_amdgcn_mfma_f32_32x32x16_bf16(al1, bh, acc1, 0, 0, 0);
        acc1 = __builtin_amdgcn_mfma_f32_32x32x16_bf16(ah1, bl, acc1, 0, 0, 0);
        if (c < 7) {
            bh = nbh; bl = nbl;
            ah0 = nh0; al0 = nl0; ah1 = nh1; al1 = nl1;
        }
    }

    // ---- segmented col-max straight from accumulators -> atomicMax ----
    const int col = nb + m;
    {
        float run = -3.4e38f;
        int curd = dsts[4 * kh];
#pragma unroll
        for (int r = 0; r < 16; ++r) {
            const int er = (r & 3) + 8 * (r >> 2) + 4 * kh;
            int d = dsts[er];
            if (d != curd) {
                if (curd >= 0)
                    atomicMax(&enc[(size_t)curd * HIDDEN + col], encf(run));
                curd = d;
                run = -3.4e38f;
            }
            run = fmaxf(run, acc0[r]);
        }
        if (curd >= 0)
            atomicMax(&enc[(size_t)curd * HIDDEN + col], encf(run));
    }
    {
        float run = -3.4e38f;
        int curd = dsts[32 + 4 * kh];
#pragma unroll
        for (int r = 0; r < 16; ++r) {
            const int er = 32 + (r & 3) + 8 * (r >> 2) + 4 * kh;
            int d = dsts[er];
            if (d != curd) {
                if (curd >= 0)
                    atomicMax(&enc[(size_t)curd * HIDDEN + col], encf(run));
                curd = d;
                run = -3.4e38f;
            }
            run = fmaxf(run, acc1[r]);
        }
        if (curd >= 0)
            atomicMax(&enc[(size_t)curd * HIDDEN + col], encf(run));
    }
}

// ---------------- launch ----------------
extern "C" void kernel_launch(void* const* d_in, const int* in_sizes, int n_in,
                              void* d_out, int out_size, void* d_ws, size_t ws_size,
                              hipStream_t stream)
{
    const float* x     = (const float*)d_in[0];
    const int*   ei    = (const int*)d_in[1];
    const float* W_emb = (const float*)d_in[2];
    const float* b_emb = (const float*)d_in[3];
    const float* W1    = (const float*)d_in[4];
    const float* b1    = (const float*)d_in[5];
    const float* W2    = (const float*)d_in[6];
    const float* b2    = (const float*)d_in[7];
    const float* W_fc  = (const float*)d_in[8];
    const float* b_fc  = (const float*)d_in[9];
    float* out = (float*)d_out;

    char* p = (char*)d_ws;
    auto alloc = [&](size_t bytes) {
        char* r = p;
        p += (bytes + 255) & ~(size_t)255;
        return r;
    };
    float* h    = (float*)alloc((size_t)N_NODES * HIDDEN * 4);
    float* Ab   = (float*)alloc((size_t)N_NODES * HIDDEN * 4);
    float* Bb   = (float*)alloc((size_t)N_NODES * HIDDEN * 4);
    unsigned int* enc = (unsigned int*)alloc((size_t)N_NODES * HIDDEN * 4);
    float* Wa   = (float*)alloc((size_t)NUM_LAYERS * 16384 * 4);
    float* Wb   = (float*)alloc((size_t)NUM_LAYERS * 16384 * 4);
    short* W2cm = (short*)alloc((size_t)NUM_LAYERS * 8 * 2 * 2048 * 2);
    int* cursor = (int*)alloc(N_NODES * 4);
    int* cnt    = (int*)alloc(N_NODES * 4);
    int* esrc   = (int*)alloc((size_t)NT * 4);
    int* edst   = (int*)alloc((size_t)NT * 4);
    int* srcN   = (int*)alloc((size_t)N_EDGES * 4);
    int* dstN   = (int*)alloc((size_t)N_EDGES * 4);
    int* flag   = (int*)alloc(4);

    const int EBLK = (N_EDGES + 255) / 256;

    k_detect<<<1, 256, 0, stream>>>(ei, flag);
    k_normalize<<<EBLK, 256, 0, stream>>>(ei, flag, srcN, dstN);
    k_zero<<<(N_NODES + 255) / 256, 256, 0, stream>>>(cnt, N_NODES);
    k_count<<<EBLK, 256, 0, stream>>>(dstN, cnt);
    k_scan<<<1, 256, 0, stream>>>(cnt, cursor);
    k_scatter<<<EBLK, 256, 0, stream>>>(srcN, dstN, cursor, esrc, edst);
    k_selfloop<<<(N_NODES + 255) / 256, 256, 0, stream>>>(cursor, esrc, edst);
    k_prepw<<<(NUM_LAYERS * 16384 + 255) / 256, 256, 0, stream>>>(W1, Wa, Wb);
    k_prepw2<<<(NUM_LAYERS * 16384 + 255) / 256, 256, 0, stream>>>(W2, W2cm);

    const int GB  = (N_NODES + 63) / 64;          // 157
    const int EG  = (NT + EB3 - 1) / EB3;         // 10157
    const int NZ  = (N_NODES * HIDDEN + 255) / 256;

    k_zero<<<NZ, 256, 0, stream>>>((int*)enc, N_NODES * HIDDEN);   // once; k_decode re-zeros
    k_gemm_nodes<NODE_DIM><<<GB, 256, 0, stream>>>(x, W_emb, b_emb, h, N_NODES);

    for (int l = 0; l < NUM_LAYERS; ++l) {
        k_gemm_ab<<<GB, 256, 0, stream>>>(h, Wa + l * 16384, Wb + l * 16384,
                                          b1 + l * 128, Ab, Bb, N_NODES);
        k_edge5<<<EG, 256, 0, stream>>>(Ab, Bb, esrc, edst,
                                        W2cm + (size_t)l * 32768, enc);
        k_decode<<<NZ, 256, 0, stream>>>(enc, b2 + l * 128, h);
    }
    k_gemm_nodes<HIDDEN><<<GB, 256, 0, stream>>>(h, W_fc, b_fc, out, N_NODES);
}

// Round 6
// 637.249 us; speedup vs baseline: 2.6292x; 1.2240x over previous
//
#include <hip/hip_runtime.h>

#define N_NODES 10000
#define N_EDGES 640000
#define NODE_DIM 64
#define HIDDEN 128
#define NUM_LAYERS 4
#define NT (N_EDGES + N_NODES)   // 650000 edge slots incl. self loops
#define EB3 64                   // edge slots per block in k_edge6

typedef __attribute__((ext_vector_type(8))) short short8v;
typedef __attribute__((ext_vector_type(4))) short short4v;
typedef __attribute__((ext_vector_type(16))) float f32x16;

// ---------------- edge dtype detection / normalization ----------------
__global__ void k_detect(const int* __restrict__ ei, int* __restrict__ flag)
{
    __shared__ int nz;
    if (threadIdx.x == 0) nz = 0;
    __syncthreads();
    int found = 0;
    for (int k = threadIdx.x; k < 2048; k += 256) {
        int pos = 2 * (k * 156) + 1;
        if (ei[pos] != 0) found = 1;
    }
    if (found) atomicOr(&nz, 1);
    __syncthreads();
    if (threadIdx.x == 0) flag[0] = nz;          // 1 = int32 layout, 0 = int64
}

__global__ void k_normalize(const int* __restrict__ ei, const int* __restrict__ flag,
                            int* __restrict__ srcN, int* __restrict__ dstN)
{
    int e = blockIdx.x * 256 + threadIdx.x;
    if (e >= N_EDGES) return;
    if (flag[0]) {
        srcN[e] = ei[e];
        dstN[e] = ei[N_EDGES + e];
    } else {
        srcN[e] = ei[2 * e];
        dstN[e] = ei[2 * (N_EDGES + e)];
    }
}

__global__ void k_zero(int* __restrict__ p, int n)
{
    int i = blockIdx.x * 256 + threadIdx.x;
    if (i < n) p[i] = 0;
}

__global__ void k_count(const int* __restrict__ dstN, int* __restrict__ cnt)
{
    int e = blockIdx.x * 256 + threadIdx.x;
    if (e < N_EDGES) atomicAdd(&cnt[dstN[e]], 1);
}

__global__ void k_scan(const int* __restrict__ cnt, int* __restrict__ cursor)
{
    __shared__ int part[256];
    const int t = threadIdx.x;
    const int CH = (N_NODES + 255) / 256;        // 40
    int lo = t * CH, hi = min(N_NODES, lo + CH);
    int s = 0;
    for (int i = lo; i < hi; ++i) s += cnt[i] + 1;
    part[t] = s;
    __syncthreads();
    for (int off = 1; off < 256; off <<= 1) {
        int v = (t >= off) ? part[t - off] : 0;
        __syncthreads();
        part[t] += v;
        __syncthreads();
    }
    int base = (t == 0) ? 0 : part[t - 1];
    for (int i = lo; i < hi; ++i) {
        cursor[i] = base;
        base += cnt[i] + 1;
    }
}

__global__ void k_scatter(const int* __restrict__ srcN, const int* __restrict__ dstN,
                          int* __restrict__ cursor,
                          int* __restrict__ esrc, int* __restrict__ edst)
{
    int e = blockIdx.x * 256 + threadIdx.x;
    if (e < N_EDGES) {
        int d = dstN[e];
        int pos = atomicAdd(&cursor[d], 1);
        esrc[pos] = srcN[e];
        edst[pos] = d;
    }
}

__global__ void k_selfloop(int* __restrict__ cursor,
                           int* __restrict__ esrc, int* __restrict__ edst)
{
    int n = blockIdx.x * 256 + threadIdx.x;
    if (n < N_NODES) {
        int pos = atomicAdd(&cursor[n], 1);
        esrc[pos] = n;
        edst[pos] = n;
    }
}

// Wa = W1[:,:128,:] - W1[:,128:,:] (x_i side);  Wb = W1[:,128:,:] (x_j side)
__global__ void k_prepw(const float* __restrict__ W1, float* __restrict__ Wa,
                        float* __restrict__ Wb)
{
    int i = blockIdx.x * 256 + threadIdx.x;      // over L*128*128
    if (i >= NUM_LAYERS * 128 * 128) return;
    int l = i >> 14, rem = i & 16383;
    float top = W1[l * 32768 + rem];
    float bot = W1[l * 32768 + 16384 + rem];
    Wa[i] = top - bot;
    Wb[i] = bot;
}

__device__ __forceinline__ unsigned short bf16rne(float f)
{
    unsigned int u = __float_as_uint(f);
    unsigned int r = u + 0x7FFFu + ((u >> 16) & 1u);
    return (unsigned short)(r >> 16);
}

// W2 -> fragment-linear hi/lo bf16, lane-contiguous:
// W2f[l][c][tile][p][lane][j]  (lane = kh*32+m holds W2[k=16c+8kh+j][n=32tile+m])
// offsets (shorts): l*32768 + c*4096 + tile*1024 + p*512 + lane*8 + j
__global__ void k_prepw2(const float* __restrict__ W2, short* __restrict__ W2f)
{
    int i = blockIdx.x * 256 + threadIdx.x;      // over L*128*128
    if (i >= NUM_LAYERS * 128 * 128) return;
    int l = i >> 14, rem = i & 16383;            // rem = k*128 + n
    int k = rem >> 7, n = rem & 127;
    float w = W2[i];
    unsigned short hs = bf16rne(w);
    float hf = __uint_as_float((unsigned int)hs << 16);
    unsigned short ls = bf16rne(w - hf);
    int c = k >> 4, kh = (k >> 3) & 1, j = k & 7;
    int tile = n >> 5, m = n & 31;
    int lane = kh * 32 + m;
    size_t base = (size_t)l * 32768 + c * 4096 + tile * 1024 + lane * 8 + j;
    W2f[base]       = (short)hs;
    W2f[base + 512] = (short)ls;
}

// decode sign-magnitude-encoded max + bias -> h; reset enc to 0 for next layer
__global__ void k_decode(unsigned int* __restrict__ enc,
                         const float* __restrict__ b2, float* __restrict__ h)
{
    int i = blockIdx.x * 256 + threadIdx.x;
    if (i >= N_NODES * HIDDEN) return;
    unsigned int u = enc[i];
    enc[i] = 0u;
    unsigned int bits = (u & 0x80000000u) ? (u ^ 0x80000000u) : ~u;
    h[i] = __uint_as_float(bits) + b2[i & (HIDDEN - 1)];
}

__device__ __forceinline__ unsigned int encf(float f)
{
    unsigned int b = __float_as_uint(f);
    return b ^ ((unsigned int)((int)b >> 31) | 0x80000000u);
}

// ---------------- node GEMM: C[M][128] = X[M][K] @ W[K][128] (+bias) ----------------
template <int K>
__global__ __launch_bounds__(256) void k_gemm_nodes(
    const float* __restrict__ X, const float* __restrict__ W,
    const float* __restrict__ bias, float* __restrict__ C, int M)
{
    constexpr int LDX = K + 4;
    __shared__ float Xs[64 * LDX];
    const int t = threadIdx.x;
    const int row0 = blockIdx.x * 64;
    constexpr int F4R = K / 4;
    for (int idx = t; idx < 64 * F4R; idx += 256) {
        int r = idx / F4R, f = idx % F4R;
        int gr = row0 + r;
        float4 v = make_float4(0.f, 0.f, 0.f, 0.f);
        if (gr < M) v = *(const float4*)(X + (size_t)gr * K + 4 * f);
        *(float4*)(Xs + r * LDX + 4 * f) = v;
    }
    __syncthreads();
    const int rg = t >> 4, cg = t & 15;
    float acc[4][8];
#pragma unroll
    for (int i = 0; i < 4; ++i)
#pragma unroll
        for (int j = 0; j < 8; ++j) acc[i][j] = 0.f;

#pragma unroll 8
    for (int k = 0; k < K; ++k) {
        float4 w0 = *(const float4*)(W + k * 128 + cg * 8);
        float4 w1 = *(const float4*)(W + k * 128 + cg * 8 + 4);
        float xs[4];
#pragma unroll
        for (int i = 0; i < 4; ++i) xs[i] = Xs[(rg * 4 + i) * LDX + k];
#pragma unroll
        for (int i = 0; i < 4; ++i) {
            acc[i][0] += xs[i] * w0.x; acc[i][1] += xs[i] * w0.y;
            acc[i][2] += xs[i] * w0.z; acc[i][3] += xs[i] * w0.w;
            acc[i][4] += xs[i] * w1.x; acc[i][5] += xs[i] * w1.y;
            acc[i][6] += xs[i] * w1.z; acc[i][7] += xs[i] * w1.w;
        }
    }
    float b[8];
#pragma unroll
    for (int j = 0; j < 8; ++j) b[j] = 0.f;
    if (bias) {
        float4 b0 = *(const float4*)(bias + cg * 8);
        float4 b1 = *(const float4*)(bias + cg * 8 + 4);
        b[0] = b0.x; b[1] = b0.y; b[2] = b0.z; b[3] = b0.w;
        b[4] = b1.x; b[5] = b1.y; b[6] = b1.z; b[7] = b1.w;
    }
#pragma unroll
    for (int i = 0; i < 4; ++i) {
        int r = row0 + rg * 4 + i;
        if (r < M) {
            float4 o0 = make_float4(acc[i][0] + b[0], acc[i][1] + b[1],
                                    acc[i][2] + b[2], acc[i][3] + b[3]);
            float4 o1 = make_float4(acc[i][4] + b[4], acc[i][5] + b[5],
                                    acc[i][6] + b[6], acc[i][7] + b[7]);
            *(float4*)(C + (size_t)r * 128 + cg * 8) = o0;
            *(float4*)(C + (size_t)r * 128 + cg * 8 + 4) = o1;
        }
    }
}

// ---------------- fused node GEMM: Ab = h@Wa + b1, Bb = h@Wb (shared Xs) ----------------
__global__ __launch_bounds__(256) void k_gemm_ab(
    const float* __restrict__ X, const float* __restrict__ WA,
    const float* __restrict__ WB, const float* __restrict__ bias,
    float* __restrict__ CA, float* __restrict__ CB, int M)
{
    __shared__ float Xs[64 * 132];
    const int t = threadIdx.x;
    const int row0 = blockIdx.x * 64;
    for (int idx = t; idx < 64 * 32; idx += 256) {
        int r = idx >> 5, f = idx & 31;
        int gr = row0 + r;
        float4 v = make_float4(0.f, 0.f, 0.f, 0.f);
        if (gr < M) v = *(const float4*)(X + (size_t)gr * 128 + 4 * f);
        *(float4*)(Xs + r * 132 + 4 * f) = v;
    }
    __syncthreads();
    const int rg = t >> 4, cg = t & 15;
    float accA[4][8], accB[4][8];
#pragma unroll
    for (int i = 0; i < 4; ++i)
#pragma unroll
        for (int j = 0; j < 8; ++j) { accA[i][j] = 0.f; accB[i][j] = 0.f; }

#pragma unroll 4
    for (int k = 0; k < 128; ++k) {
        float4 wa0 = *(const float4*)(WA + k * 128 + cg * 8);
        float4 wa1 = *(const float4*)(WA + k * 128 + cg * 8 + 4);
        float4 wb0 = *(const float4*)(WB + k * 128 + cg * 8);
        float4 wb1 = *(const float4*)(WB + k * 128 + cg * 8 + 4);
        float xs[4];
#pragma unroll
        for (int i = 0; i < 4; ++i) xs[i] = Xs[(rg * 4 + i) * 132 + k];
#pragma unroll
        for (int i = 0; i < 4; ++i) {
            accA[i][0] += xs[i] * wa0.x; accA[i][1] += xs[i] * wa0.y;
            accA[i][2] += xs[i] * wa0.z; accA[i][3] += xs[i] * wa0.w;
            accA[i][4] += xs[i] * wa1.x; accA[i][5] += xs[i] * wa1.y;
            accA[i][6] += xs[i] * wa1.z; accA[i][7] += xs[i] * wa1.w;
            accB[i][0] += xs[i] * wb0.x; accB[i][1] += xs[i] * wb0.y;
            accB[i][2] += xs[i] * wb0.z; accB[i][3] += xs[i] * wb0.w;
            accB[i][4] += xs[i] * wb1.x; accB[i][5] += xs[i] * wb1.y;
            accB[i][6] += xs[i] * wb1.z; accB[i][7] += xs[i] * wb1.w;
        }
    }
    float4 b0 = *(const float4*)(bias + cg * 8);
    float4 b1 = *(const float4*)(bias + cg * 8 + 4);
#pragma unroll
    for (int i = 0; i < 4; ++i) {
        int r = row0 + rg * 4 + i;
        if (r < M) {
            *(float4*)(CA + (size_t)r * 128 + cg * 8) =
                make_float4(accA[i][0] + b0.x, accA[i][1] + b0.y,
                            accA[i][2] + b0.z, accA[i][3] + b0.w);
            *(float4*)(CA + (size_t)r * 128 + cg * 8 + 4) =
                make_float4(accA[i][4] + b1.x, accA[i][5] + b1.y,
                            accA[i][6] + b1.z, accA[i][7] + b1.w);
            *(float4*)(CB + (size_t)r * 128 + cg * 8) =
                make_float4(accB[i][0], accB[i][1], accB[i][2], accB[i][3]);
            *(float4*)(CB + (size_t)r * 128 + cg * 8 + 4) =
                make_float4(accB[i][4], accB[i][5], accB[i][6], accB[i][7]);
        }
    }
}

// ---------------- EdgeConv, MFMA 3-term, coalesced staging + W2f ----------------
// Staging: quad (4 threads) per edge slot; thread q reads float4 at
// row*128 + r*16 + q*4 (r=0..7) -> each quad round = one 64B cacheline
// (line-transaction minimum). Fragment-linear LDS as R5 (reader unchanged).
// W2f loads are lane-contiguous (1 KB/instr). Zero barriers in k-loop.
__global__ __launch_bounds__(256, 4) void k_edge6(
    const float* __restrict__ A, const float* __restrict__ Bm,
    const int* __restrict__ esrc, const int* __restrict__ edst,
    const short* __restrict__ W2l,   // this layer: fragment-linear W2f
    unsigned int* __restrict__ enc)
{
    __shared__ __align__(16) short Ts[2048 * 8];   // 32 KB, fragment-linear
    __shared__ int dsts[EB3];

    const int t = threadIdx.x;
    const int s0 = blockIdx.x * EB3;

    // ---- stage T hi/lo: coalesced quad reads ----
    {
        const int row = t >> 2;          // edge slot within block
        const int q   = t & 3;
        const int slot = s0 + row;
        int dst = -1, src = 0;
        if (slot < NT) { dst = edst[slot]; src = esrc[slot]; }
        if (q == 0) dsts[row] = dst;
        const int sfrag = row >> 5;      // slab
        const int mrow  = row & 31;      // m within slab
        const int kh    = q >> 1;
        const int half  = q & 1;
        const int lbase = kh * 32 + mrow;

        if (dst >= 0) {
            const float* Ar = A + (size_t)dst * HIDDEN + q * 4;
            const float* Br = Bm + (size_t)src * HIDDEN + q * 4;
            float4 av[8], bv[8];
#pragma unroll
            for (int r = 0; r < 8; ++r) av[r] = *(const float4*)(Ar + r * 16);
#pragma unroll
            for (int r = 0; r < 8; ++r) bv[r] = *(const float4*)(Br + r * 16);
#pragma unroll
            for (int r = 0; r < 8; ++r) {
                float f0 = fmaxf(av[r].x + bv[r].x, 0.f);
                float f1 = fmaxf(av[r].y + bv[r].y, 0.f);
                float f2 = fmaxf(av[r].z + bv[r].z, 0.f);
                float f3 = fmaxf(av[r].w + bv[r].w, 0.f);
                unsigned short h0 = bf16rne(f0), h1 = bf16rne(f1);
                unsigned short h2 = bf16rne(f2), h3 = bf16rne(f3);
                short4v sh = {(short)h0, (short)h1, (short)h2, (short)h3};
                short4v sl;
                sl[0] = (short)bf16rne(f0 - __uint_as_float((unsigned int)h0 << 16));
                sl[1] = (short)bf16rne(f1 - __uint_as_float((unsigned int)h1 << 16));
                sl[2] = (short)bf16rne(f2 - __uint_as_float((unsigned int)h2 << 16));
                sl[3] = (short)bf16rne(f3 - __uint_as_float((unsigned int)h3 << 16));
                const int c  = r;
                const int ih = ((sfrag)     * 8 + c) * 64 + lbase;   // p=0
                const int il = ((2 + sfrag) * 8 + c) * 64 + lbase;   // p=1
                *(short4v*)(&Ts[(size_t)(ih ^ c) * 8 + half * 4]) = sh;
                *(short4v*)(&Ts[(size_t)(il ^ c) * 8 + half * 4]) = sl;
            }
        } else {
            short4v z = {0, 0, 0, 0};
#pragma unroll
            for (int r = 0; r < 8; ++r) {
                const int c  = r;
                const int ih = ((sfrag)     * 8 + c) * 64 + lbase;
                const int il = ((2 + sfrag) * 8 + c) * 64 + lbase;
                *(short4v*)(&Ts[(size_t)(ih ^ c) * 8 + half * 4]) = z;
                *(short4v*)(&Ts[(size_t)(il ^ c) * 8 + half * 4]) = z;
            }
        }
    }
    __syncthreads();   // the only block barrier

    const int lane = t & 63;
    const int wv   = t >> 6;
    const int nb   = wv * 32;            // wave's 32-col tile
    const int m    = lane & 31;
    const int kh   = lane >> 5;

    f32x16 acc0 = {0,0,0,0,0,0,0,0,0,0,0,0,0,0,0,0};   // slab 0 (rows 0-31)
    f32x16 acc1 = {0,0,0,0,0,0,0,0,0,0,0,0,0,0,0,0};   // slab 1 (rows 32-63)

    // A-frag base unit indices (chunk 0): plane p, slab s -> ((p*2+s)*8)*64 + lane
    const int b00 = 0 * 512 + lane;      // p0 s0
    const int b01 = 1 * 512 + lane;      // p0 s1
    const int b10 = 2 * 512 + lane;      // p1 s0
    const int b11 = 3 * 512 + lane;      // p1 s1

    // W2f: chunk c, tile wv, plane p at c*4096 + wv*1024 + p*512 + lane*8
    const short* Wp = W2l + (size_t)wv * 1024 + (size_t)lane * 8;

    short8v bh  = *(const short8v*)(Wp);
    short8v bl  = *(const short8v*)(Wp + 512);
    short8v ah0 = *(const short8v*)(&Ts[(size_t)b00 * 8]);
    short8v al0 = *(const short8v*)(&Ts[(size_t)b10 * 8]);
    short8v ah1 = *(const short8v*)(&Ts[(size_t)b01 * 8]);
    short8v al1 = *(const short8v*)(&Ts[(size_t)b11 * 8]);

#pragma unroll
    for (int c = 0; c < 8; ++c) {
        short8v nbh, nbl, nh0, nl0, nh1, nl1;
        if (c < 7) {                     // prefetch chunk c+1 (B global, A LDS)
            const int cn = c + 1;
            nbh = *(const short8v*)(Wp + (size_t)cn * 4096);
            nbl = *(const short8v*)(Wp + (size_t)cn * 4096 + 512);
            nh0 = *(const short8v*)(&Ts[(size_t)((b00 + cn * 64) ^ cn) * 8]);
            nl0 = *(const short8v*)(&Ts[(size_t)((b10 + cn * 64) ^ cn) * 8]);
            nh1 = *(const short8v*)(&Ts[(size_t)((b01 + cn * 64) ^ cn) * 8]);
            nl1 = *(const short8v*)(&Ts[(size_t)((b11 + cn * 64) ^ cn) * 8]);
        }
        acc0 = __builtin_amdgcn_mfma_f32_32x32x16_bf16(ah0, bh, acc0, 0, 0, 0);
        acc0 = __builtin_amdgcn_mfma_f32_32x32x16_bf16(al0, bh, acc0, 0, 0, 0);
        acc0 = __builtin_amdgcn_mfma_f32_32x32x16_bf16(ah0, bl, acc0, 0, 0, 0);
        acc1 = __builtin_amdgcn_mfma_f32_32x32x16_bf16(ah1, bh, acc1, 0, 0, 0);
        acc1 = __builtin_amdgcn_mfma_f32_32x32x16_bf16(al1, bh, acc1, 0, 0, 0);
        acc1 = __builtin_amdgcn_mfma_f32_32x32x16_bf16(ah1, bl, acc1, 0, 0, 0);
        if (c < 7) {
            bh = nbh; bl = nbl;
            ah0 = nh0; al0 = nl0; ah1 = nh1; al1 = nl1;
        }
    }

    // ---- segmented col-max straight from accumulators -> atomicMax ----
    const int col = nb + m;
    {
        float run = -3.4e38f;
        int curd = dsts[4 * kh];
#pragma unroll
        for (int r = 0; r < 16; ++r) {
            const int er = (r & 3) + 8 * (r >> 2) + 4 * kh;
            int d = dsts[er];
            if (d != curd) {
                if (curd >= 0)
                    atomicMax(&enc[(size_t)curd * HIDDEN + col], encf(run));
                curd = d;
                run = -3.4e38f;
            }
            run = fmaxf(run, acc0[r]);
        }
        if (curd >= 0)
            atomicMax(&enc[(size_t)curd * HIDDEN + col], encf(run));
    }
    {
        float run = -3.4e38f;
        int curd = dsts[32 + 4 * kh];
#pragma unroll
        for (int r = 0; r < 16; ++r) {
            const int er = 32 + (r & 3) + 8 * (r >> 2) + 4 * kh;
            int d = dsts[er];
            if (d != curd) {
                if (curd >= 0)
                    atomicMax(&enc[(size_t)curd * HIDDEN + col], encf(run));
                curd = d;
                run = -3.4e38f;
            }
            run = fmaxf(run, acc1[r]);
        }
        if (curd >= 0)
            atomicMax(&enc[(size_t)curd * HIDDEN + col], encf(run));
    }
}

// ---------------- launch ----------------
extern "C" void kernel_launch(void* const* d_in, const int* in_sizes, int n_in,
                              void* d_out, int out_size, void* d_ws, size_t ws_size,
                              hipStream_t stream)
{
    const float* x     = (const float*)d_in[0];
    const int*   ei    = (const int*)d_in[1];
    const float* W_emb = (const float*)d_in[2];
    const float* b_emb = (const float*)d_in[3];
    const float* W1    = (const float*)d_in[4];
    const float* b1    = (const float*)d_in[5];
    const float* W2    = (const float*)d_in[6];
    const float* b2    = (const float*)d_in[7];
    const float* W_fc  = (const float*)d_in[8];
    const float* b_fc  = (const float*)d_in[9];
    float* out = (float*)d_out;

    char* p = (char*)d_ws;
    auto alloc = [&](size_t bytes) {
        char* r = p;
        p += (bytes + 255) & ~(size_t)255;
        return r;
    };
    float* h    = (float*)alloc((size_t)N_NODES * HIDDEN * 4);
    float* Ab   = (float*)alloc((size_t)N_NODES * HIDDEN * 4);
    float* Bb   = (float*)alloc((size_t)N_NODES * HIDDEN * 4);
    unsigned int* enc = (unsigned int*)alloc((size_t)N_NODES * HIDDEN * 4);
    float* Wa   = (float*)alloc((size_t)NUM_LAYERS * 16384 * 4);
    float* Wb   = (float*)alloc((size_t)NUM_LAYERS * 16384 * 4);
    short* W2f  = (short*)alloc((size_t)NUM_LAYERS * 32768 * 2);
    int* cursor = (int*)alloc(N_NODES * 4);
    int* cnt    = (int*)alloc(N_NODES * 4);
    int* esrc   = (int*)alloc((size_t)NT * 4);
    int* edst   = (int*)alloc((size_t)NT * 4);
    int* srcN   = (int*)alloc((size_t)N_EDGES * 4);
    int* dstN   = (int*)alloc((size_t)N_EDGES * 4);
    int* flag   = (int*)alloc(4);

    const int EBLK = (N_EDGES + 255) / 256;

    k_detect<<<1, 256, 0, stream>>>(ei, flag);
    k_normalize<<<EBLK, 256, 0, stream>>>(ei, flag, srcN, dstN);
    k_zero<<<(N_NODES + 255) / 256, 256, 0, stream>>>(cnt, N_NODES);
    k_count<<<EBLK, 256, 0, stream>>>(dstN, cnt);
    k_scan<<<1, 256, 0, stream>>>(cnt, cursor);
    k_scatter<<<EBLK, 256, 0, stream>>>(srcN, dstN, cursor, esrc, edst);
    k_selfloop<<<(N_NODES + 255) / 256, 256, 0, stream>>>(cursor, esrc, edst);
    k_prepw<<<(NUM_LAYERS * 16384 + 255) / 256, 256, 0, stream>>>(W1, Wa, Wb);
    k_prepw2<<<(NUM_LAYERS * 16384 + 255) / 256, 256, 0, stream>>>(W2, W2f);

    const int GB  = (N_NODES + 63) / 64;          // 157
    const int EG  = (NT + EB3 - 1) / EB3;         // 10157
    const int NZ  = (N_NODES * HIDDEN + 255) / 256;

    k_zero<<<NZ, 256, 0, stream>>>((int*)enc, N_NODES * HIDDEN);   // once; k_decode re-zeros
    k_gemm_nodes<NODE_DIM><<<GB, 256, 0, stream>>>(x, W_emb, b_emb, h, N_NODES);

    for (int l = 0; l < NUM_LAYERS; ++l) {
        k_gemm_ab<<<GB, 256, 0, stream>>>(h, Wa + l * 16384, Wb + l * 16384,
                                          b1 + l * 128, Ab, Bb, N_NODES);
        k_edge6<<<EG, 256, 0, stream>>>(Ab, Bb, esrc, edst,
                                        W2f + (size_t)l * 32768, enc);
        k_decode<<<NZ, 256, 0, stream>>>(enc, b2 + l * 128, h);
    }
    k_gemm_nodes<HIDDEN><<<GB, 256, 0, stream>>>(h, W_fc, b_fc, out, N_NODES);
}